// Round 3
// baseline (5862.819 us; speedup 1.0000x reference)
//
#include <hip/hip_runtime.h>
#include <hip/hip_bf16.h>

#define NN 50000
#define NE 800000

// ---------------------------------------------------------------------------
// in-degree histogram over dst = ei[E..2E)
// ---------------------------------------------------------------------------
__global__ void k_deg(const int* __restrict__ ei, int* __restrict__ deg, int E) {
    int e = blockIdx.x * blockDim.x + threadIdx.x;
    if (e < E) atomicAdd(&deg[ei[E + e]], 1);
}

// ---------------------------------------------------------------------------
// Edge message + scatter:  agg[dst] += relu(x[src]@Wc[0:K] + ew@Wc[K:K+2] + bc)
// EPB edges per 256-thread block, NCOL threads per edge (one output col each).
// All f32.
// ---------------------------------------------------------------------------
template<int K, int NCOL, int EPB>
__global__ __launch_bounds__(256)
void k_edge(const float* __restrict__ X, const int* __restrict__ ei,
            const float* __restrict__ ew, const float* __restrict__ Wc,
            const float* __restrict__ bc, float* __restrict__ agg, int E)
{
    static_assert(NCOL * EPB == 256, "block mismatch");
    __shared__ float xs[EPB][K];
    const int t = threadIdx.x;
    const int le = t / NCOL;
    const int col = t % NCOL;
    const long e = (long)blockIdx.x * EPB + le;
    const bool valid = (e < E);
    int dst = 0;
    float ew0 = 0.f, ew1 = 0.f;
    if (valid) {
        int src = ei[e];
        dst = ei[E + e];
        ew0 = ew[2 * e];
        ew1 = ew[2 * e + 1];
        for (int k = col; k < K; k += NCOL)
            xs[le][k] = X[(size_t)src * K + k];
    }
    __syncthreads();
    if (!valid) return;
    float acc = bc[col] + ew0 * Wc[(size_t)K * NCOL + col]
                        + ew1 * Wc[(size_t)(K + 1) * NCOL + col];
#pragma unroll 8
    for (int k = 0; k < K; ++k)
        acc = fmaf(xs[le][k], Wc[k * NCOL + col], acc);
    acc = fmaxf(acc, 0.f);
    unsafeAtomicAdd(&agg[(size_t)dst * NCOL + col], acc);
}

// ---------------------------------------------------------------------------
// Node transform: out[n] = act( (agg[n]/max(deg,1)) @ W + b )
// MOUT: 1 = relu -> f32 buffer (next conv input)
//       2 = relu -> mu (f32 out), logvar (f32 out), z (f32 ws, cols 0..63)
//       3 = tanh -> f32 out
// ---------------------------------------------------------------------------
template<int K, int NCOL, int NPB, int MOUT>
__global__ __launch_bounds__(256)
void k_node(const float* __restrict__ agg, const int* __restrict__ deg,
            const float* __restrict__ W, const float* __restrict__ b,
            float* __restrict__ fo, float* __restrict__ o0,
            float* __restrict__ o1, int M)
{
    static_assert(NCOL * NPB == 256, "block mismatch");
    __shared__ float xs[NPB][K];
    const int t = threadIdx.x;
    const int ln = t / NCOL;
    const int col = t % NCOL;
    const long n = (long)blockIdx.x * NPB + ln;
    const bool valid = (n < M);
    if (valid) {
        int dg = deg[n];
        float inv = 1.0f / (float)(dg > 1 ? dg : 1);
        for (int k = col; k < K; k += NCOL)
            xs[ln][k] = agg[(size_t)n * K + k] * inv;
    }
    __syncthreads();
    if (!valid) return;
    float acc = b[col];
#pragma unroll 8
    for (int k = 0; k < K; ++k)
        acc = fmaf(xs[ln][k], W[k * NCOL + col], acc);
    if constexpr (MOUT == 1) {
        fo[(size_t)n * NCOL + col] = fmaxf(acc, 0.f);
    } else if constexpr (MOUT == 2) {
        float v = fmaxf(acc, 0.f);
        if (col < 64) {
            o0[(size_t)n * 64 + col] = v;        // mu (output, f32)
            fo[(size_t)n * 64 + col] = v;        // z  (workspace, f32, conv3 input)
        } else {
            o1[(size_t)n * 64 + (col - 64)] = v; // logvar (output, f32)
        }
    } else {
        o0[(size_t)n * NCOL + col] = tanhf(acc);
    }
}

// ---------------------------------------------------------------------------
// pet[e] = sum_i |x[src][i]-x[dst][i]|*etW[i] + ew0*etW[128] + ew1*etW[129] + etb
// 16 lanes per edge, 8 f32 per lane, shuffle reduce.
// ---------------------------------------------------------------------------
__global__ __launch_bounds__(256)
void k_pet(const float* __restrict__ x, const int* __restrict__ ei,
           const float* __restrict__ ew, const float* __restrict__ etW,
           const float* __restrict__ etb, float* __restrict__ out, int E)
{
    const int lane = threadIdx.x & 63;
    const long wg = ((long)blockIdx.x * blockDim.x + threadIdx.x) >> 6;
    const long e = wg * 4 + (lane >> 4);
    const int l16 = lane & 15;
    if (e >= E) return;
    const int s = ei[e], d = ei[E + e];
    const float4* ps = (const float4*)(x + (size_t)s * 128) + l16 * 2;
    const float4* pd = (const float4*)(x + (size_t)d * 128) + l16 * 2;
    const float4* pw = (const float4*)etW + l16 * 2;
    float4 a0 = ps[0], a1 = ps[1];
    float4 b0 = pd[0], b1 = pd[1];
    float4 w0 = pw[0], w1 = pw[1];
    float acc = fabsf(a0.x - b0.x) * w0.x + fabsf(a0.y - b0.y) * w0.y
              + fabsf(a0.z - b0.z) * w0.z + fabsf(a0.w - b0.w) * w0.w
              + fabsf(a1.x - b1.x) * w1.x + fabsf(a1.y - b1.y) * w1.y
              + fabsf(a1.z - b1.z) * w1.z + fabsf(a1.w - b1.w) * w1.w;
    acc += __shfl_xor(acc, 8);
    acc += __shfl_xor(acc, 4);
    acc += __shfl_xor(acc, 2);
    acc += __shfl_xor(acc, 1);
    if (l16 == 0)
        out[e] = acc + ew[2 * e] * etW[128] + ew[2 * e + 1] * etW[129] + etb[0];
}

// ---------------------------------------------------------------------------
extern "C" void kernel_launch(void* const* d_in, const int* in_sizes, int n_in,
                              void* d_out, int out_size, void* d_ws, size_t ws_size,
                              hipStream_t stream) {
    const float* x   = (const float*)d_in[0];
    const int*   ei  = (const int*)d_in[1];
    const float* ew  = (const float*)d_in[2];
    const float* Wc1 = (const float*)d_in[3];
    const float* bc1 = (const float*)d_in[4];
    const float* W1  = (const float*)d_in[5];
    const float* b1  = (const float*)d_in[6];
    const float* Wc2 = (const float*)d_in[7];
    const float* bc2 = (const float*)d_in[8];
    const float* W2  = (const float*)d_in[9];
    const float* b2  = (const float*)d_in[10];
    const float* Wc3 = (const float*)d_in[11];
    const float* bc3 = (const float*)d_in[12];
    const float* W3  = (const float*)d_in[13];
    const float* b3  = (const float*)d_in[14];
    const float* Wc4 = (const float*)d_in[15];
    const float* bc4 = (const float*)d_in[16];
    const float* W4  = (const float*)d_in[17];
    const float* b4  = (const float*)d_in[18];
    const float* etW = (const float*)d_in[19];
    const float* etb = (const float*)d_in[20];

    float* out   = (float*)d_out;
    float* recon = out;                              // N x 128
    float* mu    = out + (size_t)NN * 128;           // N x 64
    float* lv    = mu + (size_t)NN * 64;             // N x 64
    float* pet   = lv + (size_t)NN * 64;             // E x 1

    char* wsp = (char*)d_ws;
    float* agg = (float*)(wsp);                 // [0, 25.6M)     N x 128 f32
    float* h1f = (float*)(wsp + 25600000);      // [25.6M, 51.2M) N x 128 f32
    float* zf  = (float*)(wsp + 51200000);      // [51.2M, 64.0M) N x 64 f32
    float* df  = h1f;                           // reuse: h1f dead after conv2-edge
    int*   deg = (int*)(wsp + 64000000);        // [64.0M, 64.2M)

    const int E = NE, NV = NN;

    hipMemsetAsync(deg, 0, NV * sizeof(int), stream);
    k_deg<<<(E + 255) / 256, 256, 0, stream>>>(ei, deg, E);

    // ---- conv1: x -> h1f
    hipMemsetAsync(agg, 0, (size_t)NV * 128 * 4, stream);
    k_edge<128, 128, 2><<<(E + 1) / 2, 256, 0, stream>>>(x, ei, ew, Wc1, bc1, agg, E);
    k_node<128, 128, 2, 1><<<(NV + 1) / 2, 256, 0, stream>>>(agg, deg, W1, b1,
                                                             h1f, nullptr, nullptr, NV);

    // ---- conv2: h1f -> (mu, logvar, zf)
    hipMemsetAsync(agg, 0, (size_t)NV * 128 * 4, stream);
    k_edge<128, 128, 2><<<(E + 1) / 2, 256, 0, stream>>>(h1f, ei, ew, Wc2, bc2, agg, E);
    k_node<128, 128, 2, 2><<<(NV + 1) / 2, 256, 0, stream>>>(agg, deg, W2, b2,
                                                             zf, mu, lv, NV);

    // ---- pet (uses original x)
    k_pet<<<50000, 256, 0, stream>>>(x, ei, ew, etW, etb, pet, E);

    // ---- conv3: zf -> df
    hipMemsetAsync(agg, 0, (size_t)NV * 64 * 4, stream);
    k_edge<64, 64, 4><<<(E + 3) / 4, 256, 0, stream>>>(zf, ei, ew, Wc3, bc3, agg, E);
    k_node<64, 128, 2, 1><<<(NV + 1) / 2, 256, 0, stream>>>(agg, deg, W3, b3,
                                                            df, nullptr, nullptr, NV);

    // ---- conv4: df -> recon
    hipMemsetAsync(agg, 0, (size_t)NV * 128 * 4, stream);
    k_edge<128, 128, 2><<<(E + 1) / 2, 256, 0, stream>>>(df, ei, ew, Wc4, bc4, agg, E);
    k_node<128, 128, 2, 3><<<(NV + 1) / 2, 256, 0, stream>>>(agg, deg, W4, b4,
                                                             nullptr, recon, nullptr, NV);
}

// Round 4
// 1716.908 us; speedup vs baseline: 3.4148x; 3.4148x over previous
//
#include <hip/hip_runtime.h>
#include <hip/hip_bf16.h>

#define NN 50000
#define NE 800000

typedef __bf16 bf16x8 __attribute__((ext_vector_type(8)));
typedef float f32x4 __attribute__((ext_vector_type(4)));

__device__ __forceinline__ unsigned short f2bu(float f) {
    return __builtin_bit_cast(unsigned short, (__bf16)f);
}

// ---------------------------------------------------------------------------
// f32 -> bf16 convert (x -> xb), 8 elements per thread
// ---------------------------------------------------------------------------
__global__ void k_cvt(const float* __restrict__ x, unsigned short* __restrict__ xb, int n8) {
    int i = blockIdx.x * blockDim.x + threadIdx.x;
    if (i >= n8) return;
    float4 a = ((const float4*)x)[i * 2];
    float4 b = ((const float4*)x)[i * 2 + 1];
    bf16x8 v;
    v[0] = (__bf16)a.x; v[1] = (__bf16)a.y; v[2] = (__bf16)a.z; v[3] = (__bf16)a.w;
    v[4] = (__bf16)b.x; v[5] = (__bf16)b.y; v[6] = (__bf16)b.z; v[7] = (__bf16)b.w;
    ((uint4*)xb)[i] = __builtin_bit_cast(uint4, v);
}

// ---------------------------------------------------------------------------
// in-degree histogram over dst = ei[E..2E)
// ---------------------------------------------------------------------------
__global__ void k_deg(const int* __restrict__ ei, int* __restrict__ deg, int E) {
    int e = blockIdx.x * blockDim.x + threadIdx.x;
    if (e < E) atomicAdd(&deg[ei[E + e]], 1);
}

// ---------------------------------------------------------------------------
// MFMA edge-GEMM + scatter:
//   agg[dst[e]] += relu( Xb[src[e]] @ Wc[0:KP] + ew[e]@Wc[KP:KP+2] + bc )
// Tile = 128 edges x NOUT cols; 4 waves = 2 row-groups x 2 col-groups.
// Wc (bf16) + edge-weight rows (f32) + bias (f32) live in registers, loaded once.
// A staged in LDS in MFMA fragment-major order: for (mb,ks):
//   512-short block, layout [q=0..3][row=0..15][8 k], so lane reads are linear.
// ---------------------------------------------------------------------------
template<int KP, int NOUT>
__global__ __launch_bounds__(256, 2)
void k_edge_mfma(const unsigned short* __restrict__ Asrc, const int* __restrict__ ei,
                 const float* __restrict__ ew, const float* __restrict__ Wc,
                 const float* __restrict__ bc, float* __restrict__ agg, int E)
{
    constexpr int BLOCK_M = 128;
    constexpr int CH = KP / 8;          // 16B chunks per row
    constexpr int KSTEPS = KP / 32;
    constexpr int FM = 4;               // 4 x 16 rows per wave = 64
    constexpr int FN = NOUT / 32;       // 16-col fragments per wave

    __shared__ unsigned short Alds[BLOCK_M * KP];
    __shared__ int dstl[BLOCK_M];
    __shared__ float2 ewl[BLOCK_M];

    const int tid = threadIdx.x;
    const int lane = tid & 63;
    const int w = tid >> 6;
    const int lrow = lane & 15;          // A-row / B-col / C-col within fragment
    const int lkg = lane >> 4;           // k-group (8 k each) / C row-group
    const int wrow0 = (w >> 1) * 64;     // wave's first tile row
    const int cb0 = (w & 1) * (NOUT / 2); // wave's first col

    // ---- B fragments + epilogue constants in registers (once per block)
    bf16x8 bfr[KSTEPS][FN];
    float eb[FN], er0[FN], er1[FN];
#pragma unroll
    for (int nf = 0; nf < FN; ++nf) {
        int col = cb0 + nf * 16 + lrow;
#pragma unroll
        for (int ks = 0; ks < KSTEPS; ++ks)
#pragma unroll
            for (int j = 0; j < 8; ++j) {
                int k = ks * 32 + lkg * 8 + j;
                bfr[ks][nf][j] = (__bf16)Wc[k * NOUT + col];
            }
        eb[nf] = bc[col];
        er0[nf] = Wc[(size_t)KP * NOUT + col];
        er1[nf] = Wc[(size_t)(KP + 1) * NOUT + col];
    }

    const int ntiles = (E + BLOCK_M - 1) / BLOCK_M;
    for (int tile = blockIdx.x; tile < ntiles; tile += gridDim.x) {
        const int base = tile * BLOCK_M;
        __syncthreads();   // protect Alds/dstl/ewl against previous iteration readers
        // ---- stage A tile (gather rows, fragment-major LDS)
        for (int t = tid; t < BLOCK_M * CH; t += 256) {
            int row = t / CH;
            int c = t % CH;
            int r = base + row;
            uint4 val = make_uint4(0, 0, 0, 0);
            if (r < E) {
                int s = ei[r];
                val = *((const uint4*)(Asrc + (size_t)s * KP) + c);
                if (c == 0) {
                    dstl[row] = ei[E + r];
                    ewl[row] = ((const float2*)ew)[r];
                }
            }
            int mb = row >> 4;
            int lr = row & 15;
            int ks = c >> 2;
            int q = c & 3;
            *(uint4*)&Alds[(mb * KSTEPS + ks) * 512 + (q * 16 + lr) * 8] = val;
        }
        __syncthreads();

        // ---- MFMA main loop
        f32x4 acc[FM][FN];
#pragma unroll
        for (int mf = 0; mf < FM; ++mf)
#pragma unroll
            for (int nf = 0; nf < FN; ++nf)
                acc[mf][nf] = 0;

#pragma unroll
        for (int ks = 0; ks < KSTEPS; ++ks) {
            bf16x8 afr[FM];
#pragma unroll
            for (int mf = 0; mf < FM; ++mf) {
                int mb = (wrow0 >> 4) + mf;
                afr[mf] = *(const bf16x8*)&Alds[(mb * KSTEPS + ks) * 512 + lane * 8];
            }
#pragma unroll
            for (int mf = 0; mf < FM; ++mf)
#pragma unroll
                for (int nf = 0; nf < FN; ++nf)
                    acc[mf][nf] = __builtin_amdgcn_mfma_f32_16x16x32_bf16(
                        afr[mf], bfr[ks][nf], acc[mf][nf], 0, 0, 0);
        }

        // ---- epilogue: C/D layout col=lane&15, row=(lane>>4)*4+reg
#pragma unroll
        for (int mf = 0; mf < FM; ++mf) {
#pragma unroll
            for (int reg = 0; reg < 4; ++reg) {
                int row = wrow0 + mf * 16 + lkg * 4 + reg;
                int r = base + row;
                if (r < E) {
                    float e0 = ewl[row].x, e1 = ewl[row].y;
                    int dn = dstl[row];
#pragma unroll
                    for (int nf = 0; nf < FN; ++nf) {
                        int col = cb0 + nf * 16 + lrow;
                        float v = acc[mf][nf][reg] + e0 * er0[nf] + e1 * er1[nf] + eb[nf];
                        v = fmaxf(v, 0.f);
                        unsafeAtomicAdd(&agg[(size_t)dn * NOUT + col], v);
                    }
                }
            }
        }
    }
}

// ---------------------------------------------------------------------------
// Node transform (all-f32 math): act( (agg[n]/max(deg,1)) @ W + b )
// MOUT: 1 = relu -> bf16 ws (next conv input)
//       2 = relu -> mu f32 out (cols<64), logvar f32 out (cols>=64), z bf16 ws
//       3 = tanh -> f32 out
// ---------------------------------------------------------------------------
template<int K, int NCOL, int NPB, int MOUT>
__global__ __launch_bounds__(256)
void k_node(const float* __restrict__ agg, const int* __restrict__ deg,
            const float* __restrict__ W, const float* __restrict__ b,
            float* __restrict__ o0, float* __restrict__ o1,
            unsigned short* __restrict__ bo, int M)
{
    static_assert(NCOL * NPB == 256, "block mismatch");
    __shared__ float xs[NPB][K];
    const int t = threadIdx.x;
    const int ln = t / NCOL;
    const int col = t % NCOL;
    const long n = (long)blockIdx.x * NPB + ln;
    const bool valid = (n < M);
    if (valid) {
        int dg = deg[n];
        float inv = 1.0f / (float)(dg > 1 ? dg : 1);
        for (int k = col; k < K; k += NCOL)
            xs[ln][k] = agg[(size_t)n * K + k] * inv;
    }
    __syncthreads();
    if (!valid) return;
    float acc = b[col];
#pragma unroll 8
    for (int k = 0; k < K; ++k)
        acc = fmaf(xs[ln][k], W[k * NCOL + col], acc);
    if constexpr (MOUT == 1) {
        bo[(size_t)n * NCOL + col] = f2bu(fmaxf(acc, 0.f));
    } else if constexpr (MOUT == 2) {
        float v = fmaxf(acc, 0.f);
        if (col < 64) {
            o0[(size_t)n * 64 + col] = v;          // mu (f32 output)
            bo[(size_t)n * 64 + col] = f2bu(v);    // z  (bf16 ws, conv3 input)
        } else {
            o1[(size_t)n * 64 + (col - 64)] = v;   // logvar (f32 output)
        }
    } else {
        o0[(size_t)n * NCOL + col] = tanhf(acc);
    }
}

// ---------------------------------------------------------------------------
// pet[e] = sum_i |x[src][i]-x[dst][i]|*etW[i] + ew0*etW[128] + ew1*etW[129] + etb
// ---------------------------------------------------------------------------
__global__ __launch_bounds__(256)
void k_pet(const float* __restrict__ x, const int* __restrict__ ei,
           const float* __restrict__ ew, const float* __restrict__ etW,
           const float* __restrict__ etb, float* __restrict__ out, int E)
{
    const int lane = threadIdx.x & 63;
    const long wg = ((long)blockIdx.x * blockDim.x + threadIdx.x) >> 6;
    const long e = wg * 4 + (lane >> 4);
    const int l16 = lane & 15;
    if (e >= E) return;
    const int s = ei[e], d = ei[E + e];
    const float4* ps = (const float4*)(x + (size_t)s * 128) + l16 * 2;
    const float4* pd = (const float4*)(x + (size_t)d * 128) + l16 * 2;
    const float4* pw = (const float4*)etW + l16 * 2;
    float4 a0 = ps[0], a1 = ps[1];
    float4 b0 = pd[0], b1 = pd[1];
    float4 w0 = pw[0], w1 = pw[1];
    float acc = fabsf(a0.x - b0.x) * w0.x + fabsf(a0.y - b0.y) * w0.y
              + fabsf(a0.z - b0.z) * w0.z + fabsf(a0.w - b0.w) * w0.w
              + fabsf(a1.x - b1.x) * w1.x + fabsf(a1.y - b1.y) * w1.y
              + fabsf(a1.z - b1.z) * w1.z + fabsf(a1.w - b1.w) * w1.w;
    acc += __shfl_xor(acc, 8);
    acc += __shfl_xor(acc, 4);
    acc += __shfl_xor(acc, 2);
    acc += __shfl_xor(acc, 1);
    if (l16 == 0)
        out[e] = acc + ew[2 * e] * etW[128] + ew[2 * e + 1] * etW[129] + etb[0];
}

// ---------------------------------------------------------------------------
extern "C" void kernel_launch(void* const* d_in, const int* in_sizes, int n_in,
                              void* d_out, int out_size, void* d_ws, size_t ws_size,
                              hipStream_t stream) {
    const float* x   = (const float*)d_in[0];
    const int*   ei  = (const int*)d_in[1];
    const float* ew  = (const float*)d_in[2];
    const float* Wc1 = (const float*)d_in[3];
    const float* bc1 = (const float*)d_in[4];
    const float* W1  = (const float*)d_in[5];
    const float* b1  = (const float*)d_in[6];
    const float* Wc2 = (const float*)d_in[7];
    const float* bc2 = (const float*)d_in[8];
    const float* W2  = (const float*)d_in[9];
    const float* b2  = (const float*)d_in[10];
    const float* Wc3 = (const float*)d_in[11];
    const float* bc3 = (const float*)d_in[12];
    const float* W3  = (const float*)d_in[13];
    const float* b3  = (const float*)d_in[14];
    const float* Wc4 = (const float*)d_in[15];
    const float* bc4 = (const float*)d_in[16];
    const float* W4  = (const float*)d_in[17];
    const float* b4  = (const float*)d_in[18];
    const float* etW = (const float*)d_in[19];
    const float* etb = (const float*)d_in[20];

    float* out   = (float*)d_out;
    float* recon = out;                              // N x 128
    float* mu    = out + (size_t)NN * 128;           // N x 64
    float* lv    = mu + (size_t)NN * 64;             // N x 64
    float* pet   = lv + (size_t)NN * 64;             // E x 1

    char* wsp = (char*)d_ws;
    float* agg          = (float*)(wsp);                      // [0, 25.6M)
    unsigned short* xb  = (unsigned short*)(wsp + 25600000);  // 12.8 MB
    unsigned short* h1b = (unsigned short*)(wsp + 38400000);  // 12.8 MB
    unsigned short* zb  = (unsigned short*)(wsp + 51200000);  // 6.4 MB
    unsigned short* db  = (unsigned short*)(wsp + 57600000);  // 12.8 MB
    int* deg            = (int*)(wsp + 70400000);             // 0.2 MB

    const int E = NE, NV = NN;

    hipMemsetAsync(deg, 0, NV * sizeof(int), stream);
    k_deg<<<(E + 255) / 256, 256, 0, stream>>>(ei, deg, E);
    k_cvt<<<(800000 + 255) / 256, 256, 0, stream>>>(x, xb, 800000);

    // ---- conv1: xb -> h1b
    hipMemsetAsync(agg, 0, (size_t)NV * 128 * 4, stream);
    k_edge_mfma<128, 128><<<1280, 256, 0, stream>>>(xb, ei, ew, Wc1, bc1, agg, E);
    k_node<128, 128, 2, 1><<<(NV + 1) / 2, 256, 0, stream>>>(agg, deg, W1, b1,
                                                             nullptr, nullptr, h1b, NV);

    // ---- conv2: h1b -> (mu, logvar, zb)
    hipMemsetAsync(agg, 0, (size_t)NV * 128 * 4, stream);
    k_edge_mfma<128, 128><<<1280, 256, 0, stream>>>(h1b, ei, ew, Wc2, bc2, agg, E);
    k_node<128, 128, 2, 2><<<(NV + 1) / 2, 256, 0, stream>>>(agg, deg, W2, b2,
                                                             mu, lv, zb, NV);

    // ---- pet (uses original f32 x)
    k_pet<<<50000, 256, 0, stream>>>(x, ei, ew, etW, etb, pet, E);

    // ---- conv3: zb -> db
    hipMemsetAsync(agg, 0, (size_t)NV * 64 * 4, stream);
    k_edge_mfma<64, 64><<<1280, 256, 0, stream>>>(zb, ei, ew, Wc3, bc3, agg, E);
    k_node<64, 128, 2, 1><<<(NV + 1) / 2, 256, 0, stream>>>(agg, deg, W3, b3,
                                                            nullptr, nullptr, db, NV);

    // ---- conv4: db -> recon
    hipMemsetAsync(agg, 0, (size_t)NV * 128 * 4, stream);
    k_edge_mfma<128, 128><<<1280, 256, 0, stream>>>(db, ei, ew, Wc4, bc4, agg, E);
    k_node<128, 128, 2, 3><<<(NV + 1) / 2, 256, 0, stream>>>(agg, deg, W4, b4,
                                                             recon, nullptr, nullptr, NV);
}

// Round 5
// 1372.644 us; speedup vs baseline: 4.2712x; 1.2508x over previous
//
#include <hip/hip_runtime.h>
#include <hip/hip_bf16.h>

#define NN 50000
#define NE 800000

typedef __bf16 bf16x8 __attribute__((ext_vector_type(8)));
typedef float f32x4 __attribute__((ext_vector_type(4)));

__device__ __forceinline__ unsigned short f2bu(float f) {
    return __builtin_bit_cast(unsigned short, (__bf16)f);
}

// ---------------------------------------------------------------------------
// f32 -> bf16 convert (x -> xb), 8 elements per thread
// ---------------------------------------------------------------------------
__global__ void k_cvt(const float* __restrict__ x, unsigned short* __restrict__ xb, int n8) {
    int i = blockIdx.x * blockDim.x + threadIdx.x;
    if (i >= n8) return;
    float4 a = ((const float4*)x)[i * 2];
    float4 b = ((const float4*)x)[i * 2 + 1];
    bf16x8 v;
    v[0] = (__bf16)a.x; v[1] = (__bf16)a.y; v[2] = (__bf16)a.z; v[3] = (__bf16)a.w;
    v[4] = (__bf16)b.x; v[5] = (__bf16)b.y; v[6] = (__bf16)b.z; v[7] = (__bf16)b.w;
    ((uint4*)xb)[i] = __builtin_bit_cast(uint4, v);
}

// ---------------------------------------------------------------------------
// in-degree histogram over dst = ei[E..2E)
// ---------------------------------------------------------------------------
__global__ void k_deg(const int* __restrict__ ei, int* __restrict__ deg, int E) {
    int e = blockIdx.x * blockDim.x + threadIdx.x;
    if (e < E) atomicAdd(&deg[ei[E + e]], 1);
}

// ---------------------------------------------------------------------------
// exclusive prefix sum of deg -> cursor (single 256-thread block, n=50000)
// ---------------------------------------------------------------------------
__global__ void k_scan(const int* __restrict__ deg, int* __restrict__ cursor, int n) {
    __shared__ int part[256];
    const int t = threadIdx.x;
    const int CHUNK = (n + 255) / 256;
    const int lo = t * CHUNK;
    const int hi = (lo + CHUNK < n) ? lo + CHUNK : n;
    int s = 0;
    for (int i = lo; i < hi; ++i) s += deg[i];
    part[t] = s;
    __syncthreads();
    int val = s;
    for (int off = 1; off < 256; off <<= 1) {
        int y = (t >= off) ? part[t - off] : 0;
        __syncthreads();
        val += y;
        part[t] = val;
        __syncthreads();
    }
    int run = val - s;   // exclusive prefix at chunk start
    for (int i = lo; i < hi; ++i) { cursor[i] = run; run += deg[i]; }
}

// ---------------------------------------------------------------------------
// scatter edges into dst-sorted order using cursor (= segment starts)
// ---------------------------------------------------------------------------
__global__ void k_scatter(const int* __restrict__ ei, const float* __restrict__ ew,
                          int* __restrict__ cursor, int* __restrict__ srcS,
                          int* __restrict__ dstS, float2* __restrict__ ewS, int E) {
    int e = blockIdx.x * blockDim.x + threadIdx.x;
    if (e >= E) return;
    int d = ei[E + e];
    int s = atomicAdd(&cursor[d], 1);
    srcS[s] = ei[e];
    dstS[s] = d;
    ewS[s] = ((const float2*)ew)[e];
}

// ---------------------------------------------------------------------------
// MFMA edge-GEMM over dst-SORTED edges + run-merged atomic scatter:
//   agg[dstS[s]] += relu( Xb[srcS[s]] @ Wc[0:KP] + ewS[s]@Wc[KP:KP+2] + bc )
// Tile = 128 edges x NOUT; 4 waves (2 row-groups x 2 col-groups); Wc in regs.
// A staged fragment-major in LDS, 520-short padded blocks + ^(q<<1) swizzle
// (write unit (q*16+lr)^(q<<1), read unit lane^(lkg<<1) — same function).
// Epilogue: lane's 4 regs = 4 consecutive sorted rows -> in-register run-merge,
// one atomic per distinct dst run (~3.4x fewer atomics).
// Requires E % 128 == 0 (NE=800000 -> 6250 tiles exactly).
// ---------------------------------------------------------------------------
template<int KP, int NOUT>
__global__ __launch_bounds__(256, 2)
void k_edge_mfma(const unsigned short* __restrict__ Xb, const int* __restrict__ srcS,
                 const int* __restrict__ dstS, const float2* __restrict__ ewS,
                 const float* __restrict__ Wc, const float* __restrict__ bc,
                 float* __restrict__ agg, int E)
{
    constexpr int BLOCK_M = 128;
    constexpr int CH = KP / 8;          // 16B chunks per row
    constexpr int KSTEPS = KP / 32;
    constexpr int FM = 4;
    constexpr int FN = NOUT / 32;
    constexpr int BLK = 520;            // 64 16B-units + 1 pad unit (in shorts)

    __shared__ unsigned short Alds[(BLOCK_M / 16) * KSTEPS * BLK];
    __shared__ int dstl[BLOCK_M];
    __shared__ float2 ewl[BLOCK_M];

    const int tid = threadIdx.x;
    const int lane = tid & 63;
    const int w = tid >> 6;
    const int lrow = lane & 15;
    const int lkg = lane >> 4;
    const int wrow0 = (w >> 1) * 64;
    const int cb0 = (w & 1) * (NOUT / 2);

    // ---- B fragments + epilogue constants in registers (once per block)
    bf16x8 bfr[KSTEPS][FN];
    float eb[FN], er0[FN], er1[FN];
#pragma unroll
    for (int nf = 0; nf < FN; ++nf) {
        int col = cb0 + nf * 16 + lrow;
#pragma unroll
        for (int ks = 0; ks < KSTEPS; ++ks)
#pragma unroll
            for (int j = 0; j < 8; ++j) {
                int k = ks * 32 + lkg * 8 + j;
                bfr[ks][nf][j] = (__bf16)Wc[k * NOUT + col];
            }
        eb[nf] = bc[col];
        er0[nf] = Wc[(size_t)KP * NOUT + col];
        er1[nf] = Wc[(size_t)(KP + 1) * NOUT + col];
    }

    const int ntiles = E / BLOCK_M;
    for (int tile = blockIdx.x; tile < ntiles; tile += gridDim.x) {
        const int base = tile * BLOCK_M;
        __syncthreads();
        // ---- stage A tile (gather sorted rows, swizzled fragment-major LDS)
        for (int t = tid; t < BLOCK_M * CH; t += 256) {
            int row = t / CH;
            int c = t % CH;
            int r = base + row;
            int s = srcS[r];
            uint4 val = *((const uint4*)(Xb + (size_t)s * KP) + c);
            if (c == 0) {
                dstl[row] = dstS[r];
                ewl[row] = ewS[r];
            }
            int mb = row >> 4, lr = row & 15, ks = c >> 2, q = c & 3;
            int unit = (q * 16 + lr) ^ (q << 1);
            *(uint4*)&Alds[(mb * KSTEPS + ks) * BLK + unit * 8] = val;
        }
        __syncthreads();

        // ---- MFMA main loop
        f32x4 acc[FM][FN];
#pragma unroll
        for (int mf = 0; mf < FM; ++mf)
#pragma unroll
            for (int nf = 0; nf < FN; ++nf)
                acc[mf][nf] = 0;

        const int runit = lane ^ (lkg << 1);
#pragma unroll
        for (int ks = 0; ks < KSTEPS; ++ks) {
            bf16x8 afr[FM];
#pragma unroll
            for (int mf = 0; mf < FM; ++mf) {
                int mb = (wrow0 >> 4) + mf;
                afr[mf] = *(const bf16x8*)&Alds[(mb * KSTEPS + ks) * BLK + runit * 8];
            }
#pragma unroll
            for (int mf = 0; mf < FM; ++mf)
#pragma unroll
                for (int nf = 0; nf < FN; ++nf)
                    acc[mf][nf] = __builtin_amdgcn_mfma_f32_16x16x32_bf16(
                        afr[mf], bfr[ks][nf], acc[mf][nf], 0, 0, 0);
        }

        // ---- epilogue: 4 consecutive sorted rows per lane -> run-merge atomics
#pragma unroll
        for (int mf = 0; mf < FM; ++mf) {
            const int rq = wrow0 + mf * 16 + lkg * 4;
            const int d0 = dstl[rq], d1 = dstl[rq + 1], d2 = dstl[rq + 2], d3 = dstl[rq + 3];
            const float2 w0 = ewl[rq], w1 = ewl[rq + 1], w2 = ewl[rq + 2], w3 = ewl[rq + 3];
#pragma unroll
            for (int nf = 0; nf < FN; ++nf) {
                int col = cb0 + nf * 16 + lrow;
                float v0 = fmaxf(acc[mf][nf][0] + w0.x * er0[nf] + w0.y * er1[nf] + eb[nf], 0.f);
                float v1 = fmaxf(acc[mf][nf][1] + w1.x * er0[nf] + w1.y * er1[nf] + eb[nf], 0.f);
                float v2 = fmaxf(acc[mf][nf][2] + w2.x * er0[nf] + w2.y * er1[nf] + eb[nf], 0.f);
                float v3 = fmaxf(acc[mf][nf][3] + w3.x * er0[nf] + w3.y * er1[nf] + eb[nf], 0.f);
                float run = v0;
                if (d1 == d0) run += v1;
                else { unsafeAtomicAdd(&agg[(size_t)d0 * NOUT + col], run); run = v1; }
                if (d2 == d1) run += v2;
                else { unsafeAtomicAdd(&agg[(size_t)d1 * NOUT + col], run); run = v2; }
                if (d3 == d2) run += v3;
                else { unsafeAtomicAdd(&agg[(size_t)d2 * NOUT + col], run); run = v3; }
                unsafeAtomicAdd(&agg[(size_t)d3 * NOUT + col], run);
            }
        }
    }
}

// ---------------------------------------------------------------------------
// MFMA node-GEMM: act( (agg[n]/max(deg,1)) @ W + b ), dense rows, no atomics.
// MOUT: 1 = relu -> bf16 ws
//       2 = relu -> mu f32 (col<64) + zb bf16 (col<64), logvar f32 (col>=64)
//       3 = tanh -> f32 out
// ---------------------------------------------------------------------------
template<int KP, int NOUT, int MOUT>
__global__ __launch_bounds__(256, 2)
void k_node_mfma(const float* __restrict__ aggIn, const int* __restrict__ deg,
                 const float* __restrict__ W, const float* __restrict__ bias,
                 float* __restrict__ o0, float* __restrict__ o1,
                 unsigned short* __restrict__ bo, int M)
{
    constexpr int BLOCK_M = 128;
    constexpr int CH = KP / 8;
    constexpr int KSTEPS = KP / 32;
    constexpr int FM = 4;
    constexpr int FN = NOUT / 32;
    constexpr int BLK = 520;

    __shared__ unsigned short Alds[(BLOCK_M / 16) * KSTEPS * BLK];

    const int tid = threadIdx.x;
    const int lane = tid & 63;
    const int w = tid >> 6;
    const int lrow = lane & 15;
    const int lkg = lane >> 4;
    const int wrow0 = (w >> 1) * 64;
    const int cb0 = (w & 1) * (NOUT / 2);

    bf16x8 bfr[KSTEPS][FN];
    float eb[FN];
#pragma unroll
    for (int nf = 0; nf < FN; ++nf) {
        int col = cb0 + nf * 16 + lrow;
#pragma unroll
        for (int ks = 0; ks < KSTEPS; ++ks)
#pragma unroll
            for (int j = 0; j < 8; ++j) {
                int k = ks * 32 + lkg * 8 + j;
                bfr[ks][nf][j] = (__bf16)W[k * NOUT + col];
            }
        eb[nf] = bias[col];
    }

    const int ntiles = (M + BLOCK_M - 1) / BLOCK_M;
    for (int tile = blockIdx.x; tile < ntiles; tile += gridDim.x) {
        const int base = tile * BLOCK_M;
        __syncthreads();
        for (int t = tid; t < BLOCK_M * CH; t += 256) {
            int row = t / CH;
            int c = t % CH;
            int r = base + row;
            uint4 val = make_uint4(0, 0, 0, 0);
            if (r < M) {
                int dg = deg[r];
                float inv = 1.0f / (float)(dg > 1 ? dg : 1);
                const float4* p = (const float4*)(aggIn + (size_t)r * KP) + c * 2;
                float4 a = p[0], b = p[1];
                bf16x8 bv;
                bv[0] = (__bf16)(a.x * inv); bv[1] = (__bf16)(a.y * inv);
                bv[2] = (__bf16)(a.z * inv); bv[3] = (__bf16)(a.w * inv);
                bv[4] = (__bf16)(b.x * inv); bv[5] = (__bf16)(b.y * inv);
                bv[6] = (__bf16)(b.z * inv); bv[7] = (__bf16)(b.w * inv);
                val = __builtin_bit_cast(uint4, bv);
            }
            int mb = row >> 4, lr = row & 15, ks = c >> 2, q = c & 3;
            int unit = (q * 16 + lr) ^ (q << 1);
            *(uint4*)&Alds[(mb * KSTEPS + ks) * BLK + unit * 8] = val;
        }
        __syncthreads();

        f32x4 acc[FM][FN];
#pragma unroll
        for (int mf = 0; mf < FM; ++mf)
#pragma unroll
            for (int nf = 0; nf < FN; ++nf)
                acc[mf][nf] = 0;

        const int runit = lane ^ (lkg << 1);
#pragma unroll
        for (int ks = 0; ks < KSTEPS; ++ks) {
            bf16x8 afr[FM];
#pragma unroll
            for (int mf = 0; mf < FM; ++mf) {
                int mb = (wrow0 >> 4) + mf;
                afr[mf] = *(const bf16x8*)&Alds[(mb * KSTEPS + ks) * BLK + runit * 8];
            }
#pragma unroll
            for (int mf = 0; mf < FM; ++mf)
#pragma unroll
                for (int nf = 0; nf < FN; ++nf)
                    acc[mf][nf] = __builtin_amdgcn_mfma_f32_16x16x32_bf16(
                        afr[mf], bfr[ks][nf], acc[mf][nf], 0, 0, 0);
        }

#pragma unroll
        for (int mf = 0; mf < FM; ++mf) {
#pragma unroll
            for (int reg = 0; reg < 4; ++reg) {
                int row = wrow0 + mf * 16 + lkg * 4 + reg;
                int r = base + row;
                if (r < M) {
#pragma unroll
                    for (int nf = 0; nf < FN; ++nf) {
                        int col = cb0 + nf * 16 + lrow;
                        float tv = acc[mf][nf][reg] + eb[nf];
                        if constexpr (MOUT == 1) {
                            bo[(size_t)r * NOUT + col] = f2bu(fmaxf(tv, 0.f));
                        } else if constexpr (MOUT == 2) {
                            float v = fmaxf(tv, 0.f);
                            if (col < 64) {
                                o0[(size_t)r * 64 + col] = v;        // mu
                                bo[(size_t)r * 64 + col] = f2bu(v);  // z
                            } else {
                                o1[(size_t)r * 64 + (col - 64)] = v; // logvar
                            }
                        } else {
                            o0[(size_t)r * NOUT + col] = tanhf(tv);
                        }
                    }
                }
            }
        }
    }
}

// ---------------------------------------------------------------------------
// pet from bf16 xb: 16 lanes/edge, 8 bf16 per lane, shuffle reduce
// ---------------------------------------------------------------------------
__global__ __launch_bounds__(256)
void k_pet(const unsigned short* __restrict__ xb, const int* __restrict__ ei,
           const float* __restrict__ ew, const float* __restrict__ etW,
           const float* __restrict__ etb, float* __restrict__ out, int E)
{
    const int lane = threadIdx.x & 63;
    const long wg = ((long)blockIdx.x * blockDim.x + threadIdx.x) >> 6;
    const long e = wg * 4 + (lane >> 4);
    const int l16 = lane & 15;
    if (e >= E) return;
    const int s = ei[e], d = ei[E + e];
    uint4 av = ((const uint4*)(xb + (size_t)s * 128))[l16];
    uint4 bv = ((const uint4*)(xb + (size_t)d * 128))[l16];
    bf16x8 a = __builtin_bit_cast(bf16x8, av);
    bf16x8 b = __builtin_bit_cast(bf16x8, bv);
    float4 w0 = ((const float4*)etW)[l16 * 2];
    float4 w1 = ((const float4*)etW)[l16 * 2 + 1];
    float acc = fabsf((float)a[0] - (float)b[0]) * w0.x
              + fabsf((float)a[1] - (float)b[1]) * w0.y
              + fabsf((float)a[2] - (float)b[2]) * w0.z
              + fabsf((float)a[3] - (float)b[3]) * w0.w
              + fabsf((float)a[4] - (float)b[4]) * w1.x
              + fabsf((float)a[5] - (float)b[5]) * w1.y
              + fabsf((float)a[6] - (float)b[6]) * w1.z
              + fabsf((float)a[7] - (float)b[7]) * w1.w;
    acc += __shfl_xor(acc, 8);
    acc += __shfl_xor(acc, 4);
    acc += __shfl_xor(acc, 2);
    acc += __shfl_xor(acc, 1);
    if (l16 == 0)
        out[e] = acc + ew[2 * e] * etW[128] + ew[2 * e + 1] * etW[129] + etb[0];
}

// ---------------------------------------------------------------------------
extern "C" void kernel_launch(void* const* d_in, const int* in_sizes, int n_in,
                              void* d_out, int out_size, void* d_ws, size_t ws_size,
                              hipStream_t stream) {
    const float* x   = (const float*)d_in[0];
    const int*   ei  = (const int*)d_in[1];
    const float* ew  = (const float*)d_in[2];
    const float* Wc1 = (const float*)d_in[3];
    const float* bc1 = (const float*)d_in[4];
    const float* W1  = (const float*)d_in[5];
    const float* b1  = (const float*)d_in[6];
    const float* Wc2 = (const float*)d_in[7];
    const float* bc2 = (const float*)d_in[8];
    const float* W2  = (const float*)d_in[9];
    const float* b2  = (const float*)d_in[10];
    const float* Wc3 = (const float*)d_in[11];
    const float* bc3 = (const float*)d_in[12];
    const float* W3  = (const float*)d_in[13];
    const float* b3  = (const float*)d_in[14];
    const float* Wc4 = (const float*)d_in[15];
    const float* bc4 = (const float*)d_in[16];
    const float* W4  = (const float*)d_in[17];
    const float* b4  = (const float*)d_in[18];
    const float* etW = (const float*)d_in[19];
    const float* etb = (const float*)d_in[20];

    float* out   = (float*)d_out;
    float* recon = out;                              // N x 128
    float* mu    = out + (size_t)NN * 128;           // N x 64
    float* lv    = mu + (size_t)NN * 64;             // N x 64
    float* pet   = lv + (size_t)NN * 64;             // E x 1

    char* wsp = (char*)d_ws;
    float* agg          = (float*)(wsp);                      // 25.6 MB
    unsigned short* xb  = (unsigned short*)(wsp + 25600000);  // 12.8 MB
    unsigned short* h1b = (unsigned short*)(wsp + 38400000);  // 12.8 MB
    unsigned short* zb  = (unsigned short*)(wsp + 51200000);  // 6.4 MB
    unsigned short* db  = (unsigned short*)(wsp + 57600000);  // 12.8 MB
    int* deg            = (int*)(wsp + 70400000);             // 0.2 MB
    int* cursor         = (int*)(wsp + 70600000);             // 0.2 MB
    int* srcS           = (int*)(wsp + 70800000);             // 3.2 MB
    int* dstS           = (int*)(wsp + 74000000);             // 3.2 MB
    float2* ewS         = (float2*)(wsp + 77200000);          // 6.4 MB

    const int E = NE, NV = NN;

    // ---- precompute: degree, scan, dst-sorted edge arrays, bf16 x
    hipMemsetAsync(deg, 0, NV * sizeof(int), stream);
    k_deg<<<(E + 255) / 256, 256, 0, stream>>>(ei, deg, E);
    k_scan<<<1, 256, 0, stream>>>(deg, cursor, NV);
    k_scatter<<<(E + 255) / 256, 256, 0, stream>>>(ei, ew, cursor, srcS, dstS, ewS, E);
    k_cvt<<<(800000 + 255) / 256, 256, 0, stream>>>(x, xb, 800000);

    // ---- conv1: xb -> h1b
    hipMemsetAsync(agg, 0, (size_t)NV * 128 * 4, stream);
    k_edge_mfma<128, 128><<<1280, 256, 0, stream>>>(xb, srcS, dstS, ewS, Wc1, bc1, agg, E);
    k_node_mfma<128, 128, 1><<<391, 256, 0, stream>>>(agg, deg, W1, b1,
                                                      nullptr, nullptr, h1b, NV);

    // ---- conv2: h1b -> (mu, logvar, zb)
    hipMemsetAsync(agg, 0, (size_t)NV * 128 * 4, stream);
    k_edge_mfma<128, 128><<<1280, 256, 0, stream>>>(h1b, srcS, dstS, ewS, Wc2, bc2, agg, E);
    k_node_mfma<128, 128, 2><<<391, 256, 0, stream>>>(agg, deg, W2, b2,
                                                      mu, lv, zb, NV);

    // ---- pet (bf16 xb)
    k_pet<<<50000, 256, 0, stream>>>(xb, ei, ew, etW, etb, pet, E);

    // ---- conv3: zb -> db
    hipMemsetAsync(agg, 0, (size_t)NV * 64 * 4, stream);
    k_edge_mfma<64, 64><<<1280, 256, 0, stream>>>(zb, srcS, dstS, ewS, Wc3, bc3, agg, E);
    k_node_mfma<64, 128, 1><<<391, 256, 0, stream>>>(agg, deg, W3, b3,
                                                     nullptr, nullptr, db, NV);

    // ---- conv4: db -> recon
    hipMemsetAsync(agg, 0, (size_t)NV * 128 * 4, stream);
    k_edge_mfma<128, 128><<<1280, 256, 0, stream>>>(db, srcS, dstS, ewS, Wc4, bc4, agg, E);
    k_node_mfma<128, 128, 3><<<391, 256, 0, stream>>>(agg, deg, W4, b4,
                                                      recon, nullptr, nullptr, NV);
}

// Round 6
// 1350.156 us; speedup vs baseline: 4.3423x; 1.0167x over previous
//
#include <hip/hip_runtime.h>
#include <hip/hip_bf16.h>

#define NN 50000
#define NE 800000

typedef __bf16 bf16x8 __attribute__((ext_vector_type(8)));
typedef float f32x4 __attribute__((ext_vector_type(4)));

typedef const __attribute__((address_space(1))) unsigned int* gas_t;
typedef __attribute__((address_space(3))) unsigned int* las_t;

__device__ __forceinline__ unsigned short f2bu(float f) {
    return __builtin_bit_cast(unsigned short, (__bf16)f);
}

// ---------------------------------------------------------------------------
// f32 -> bf16 convert (x -> xb), 8 elements per thread
// ---------------------------------------------------------------------------
__global__ void k_cvt(const float* __restrict__ x, unsigned short* __restrict__ xb, int n8) {
    int i = blockIdx.x * blockDim.x + threadIdx.x;
    if (i >= n8) return;
    float4 a = ((const float4*)x)[i * 2];
    float4 b = ((const float4*)x)[i * 2 + 1];
    bf16x8 v;
    v[0] = (__bf16)a.x; v[1] = (__bf16)a.y; v[2] = (__bf16)a.z; v[3] = (__bf16)a.w;
    v[4] = (__bf16)b.x; v[5] = (__bf16)b.y; v[6] = (__bf16)b.z; v[7] = (__bf16)b.w;
    ((uint4*)xb)[i] = __builtin_bit_cast(uint4, v);
}

// ---------------------------------------------------------------------------
// in-degree histogram over dst = ei[E..2E)
// ---------------------------------------------------------------------------
__global__ void k_deg(const int* __restrict__ ei, int* __restrict__ deg, int E) {
    int e = blockIdx.x * blockDim.x + threadIdx.x;
    if (e < E) atomicAdd(&deg[ei[E + e]], 1);
}

// ---------------------------------------------------------------------------
// exclusive prefix sum of deg -> cursor (single 256-thread block, n=50000)
// ---------------------------------------------------------------------------
__global__ void k_scan(const int* __restrict__ deg, int* __restrict__ cursor, int n) {
    __shared__ int part[256];
    const int t = threadIdx.x;
    const int CHUNK = (n + 255) / 256;
    const int lo = t * CHUNK;
    const int hi = (lo + CHUNK < n) ? lo + CHUNK : n;
    int s = 0;
    for (int i = lo; i < hi; ++i) s += deg[i];
    part[t] = s;
    __syncthreads();
    int val = s;
    for (int off = 1; off < 256; off <<= 1) {
        int y = (t >= off) ? part[t - off] : 0;
        __syncthreads();
        val += y;
        part[t] = val;
        __syncthreads();
    }
    int run = val - s;   // exclusive prefix at chunk start
    for (int i = lo; i < hi; ++i) { cursor[i] = run; run += deg[i]; }
}

// ---------------------------------------------------------------------------
// scatter edges into dst-sorted order using cursor (= segment starts)
// ---------------------------------------------------------------------------
__global__ void k_scatter(const int* __restrict__ ei, const float* __restrict__ ew,
                          int* __restrict__ cursor, int* __restrict__ srcS,
                          int* __restrict__ dstS, float2* __restrict__ ewS, int E) {
    int e = blockIdx.x * blockDim.x + threadIdx.x;
    if (e >= E) return;
    int d = ei[E + e];
    int s = atomicAdd(&cursor[d], 1);
    srcS[s] = ei[e];
    dstS[s] = d;
    ewS[s] = ((const float2*)ew)[e];
}

// ---------------------------------------------------------------------------
// DMA staging: one global_load_lds_dwordx4 per (mb,ks) 1KB fragment block.
// LDS layout per block: unit u = q*16+lr (q = k-chunk within ks, lr = row)
// = exactly lane index -> wave-uniform base + lane*16, per-lane global addr.
// ---------------------------------------------------------------------------
template<int KP>
__device__ __forceinline__ void stage_edge(const unsigned short* __restrict__ Xb,
                                           const int* __restrict__ srcS,
                                           int base, int w, int lane,
                                           unsigned short* buf)
{
    constexpr int KSTEPS = KP / 32;
    constexpr int PW = 2 * KSTEPS;          // (8 mb * KSTEPS) / 4 waves
    const int lr = lane & 15;
    const int ch = lane >> 4;
#pragma unroll
    for (int i = 0; i < PW; ++i) {
        const int idx = w * PW + i;
        const int mb = idx / KSTEPS, ks = idx % KSTEPS;
        const int s = srcS[base + mb * 16 + lr];
        const unsigned short* g = Xb + (size_t)s * KP + (ks * 4 + ch) * 8;
        unsigned short* l = buf + idx * 512;
        __builtin_amdgcn_global_load_lds((gas_t)(const void*)g, (las_t)(void*)l, 16, 0, 0);
    }
}

// ---------------------------------------------------------------------------
// MFMA edge-GEMM over dst-SORTED edges + run-merged atomic scatter.
// Double-buffered (A0/A1 distinct arrays), DMA-staged, prefetch t+1 under
// compute of t; the only drain is __syncthreads()'s vmcnt(0) at loop top.
// Requires E % 128 == 0 (800000/128 = 6250 tiles).
// ---------------------------------------------------------------------------
template<int KP, int NOUT>
__global__ __launch_bounds__(256, 2)
void k_edge_mfma(const unsigned short* __restrict__ Xb, const int* __restrict__ srcS,
                 const int* __restrict__ dstS, const float2* __restrict__ ewS,
                 const float* __restrict__ Wc, const float* __restrict__ bc,
                 float* __restrict__ agg, int E)
{
    constexpr int KSTEPS = KP / 32;
    constexpr int FM = 4;
    constexpr int FN = NOUT / 32;
    constexpr int SZ = 8 * KSTEPS * 512;   // shorts per buffer

    __shared__ __align__(16) unsigned short A0[SZ];
    __shared__ __align__(16) unsigned short A1[SZ];

    const int tid = threadIdx.x;
    const int lane = tid & 63;
    const int w = tid >> 6;
    const int lrow = lane & 15;
    const int lkg = lane >> 4;
    const int wrow0 = (w >> 1) * 64;
    const int cb0 = (w & 1) * (NOUT / 2);

    // ---- B fragments + epilogue constants in registers (once per block)
    bf16x8 bfr[KSTEPS][FN];
    float eb[FN], er0[FN], er1[FN];
#pragma unroll
    for (int nf = 0; nf < FN; ++nf) {
        int col = cb0 + nf * 16 + lrow;
#pragma unroll
        for (int ks = 0; ks < KSTEPS; ++ks)
#pragma unroll
            for (int j = 0; j < 8; ++j) {
                int k = ks * 32 + lkg * 8 + j;
                bfr[ks][nf][j] = (__bf16)Wc[k * NOUT + col];
            }
        eb[nf] = bc[col];
        er0[nf] = Wc[(size_t)KP * NOUT + col];
        er1[nf] = Wc[(size_t)(KP + 1) * NOUT + col];
    }

    // ---- per-tile compute (reads one LDS buffer, atomics to agg)
    auto compute = [&](const unsigned short* __restrict__ buf, int base) {
        f32x4 acc[FM][FN];
#pragma unroll
        for (int mf = 0; mf < FM; ++mf)
#pragma unroll
            for (int nf = 0; nf < FN; ++nf)
                acc[mf][nf] = 0;

#pragma unroll
        for (int ks = 0; ks < KSTEPS; ++ks) {
            bf16x8 afr[FM];
#pragma unroll
            for (int mf = 0; mf < FM; ++mf) {
                int mb = (wrow0 >> 4) + mf;
                afr[mf] = *(const bf16x8*)&buf[(mb * KSTEPS + ks) * 512 + lane * 8];
            }
#pragma unroll
            for (int mf = 0; mf < FM; ++mf)
#pragma unroll
                for (int nf = 0; nf < FN; ++nf)
                    acc[mf][nf] = __builtin_amdgcn_mfma_f32_16x16x32_bf16(
                        afr[mf], bfr[ks][nf], acc[mf][nf], 0, 0, 0);
        }

        // epilogue: 4 consecutive sorted rows per lane -> run-merged atomics
#pragma unroll
        for (int mf = 0; mf < FM; ++mf) {
            const int rq = base + wrow0 + mf * 16 + lkg * 4;
            const int4 dd = *(const int4*)(dstS + rq);
            const float4 ea = *(const float4*)((const float*)ewS + 2 * rq);
            const float4 ec = *(const float4*)((const float*)ewS + 2 * rq + 4);
#pragma unroll
            for (int nf = 0; nf < FN; ++nf) {
                int col = cb0 + nf * 16 + lrow;
                float v0 = fmaxf(acc[mf][nf][0] + ea.x * er0[nf] + ea.y * er1[nf] + eb[nf], 0.f);
                float v1 = fmaxf(acc[mf][nf][1] + ea.z * er0[nf] + ea.w * er1[nf] + eb[nf], 0.f);
                float v2 = fmaxf(acc[mf][nf][2] + ec.x * er0[nf] + ec.y * er1[nf] + eb[nf], 0.f);
                float v3 = fmaxf(acc[mf][nf][3] + ec.z * er0[nf] + ec.w * er1[nf] + eb[nf], 0.f);
                float run = v0;
                if (dd.y == dd.x) run += v1;
                else { unsafeAtomicAdd(&agg[(size_t)dd.x * NOUT + col], run); run = v1; }
                if (dd.z == dd.y) run += v2;
                else { unsafeAtomicAdd(&agg[(size_t)dd.y * NOUT + col], run); run = v2; }
                if (dd.w == dd.z) run += v3;
                else { unsafeAtomicAdd(&agg[(size_t)dd.z * NOUT + col], run); run = v3; }
                unsafeAtomicAdd(&agg[(size_t)dd.w * NOUT + col], run);
            }
        }
    };

    const int ntiles = E / 128;
    const int stride = gridDim.x;
    int tile = blockIdx.x;
    if (tile < ntiles) stage_edge<KP>(Xb, srcS, tile * 128, w, lane, A0);
    bool use0 = true;
    while (tile < ntiles) {
        const int nxt = tile + stride;
        __syncthreads();   // drains vmcnt(0): current buffer's DMA + old atomics
        if (use0) {
            if (nxt < ntiles) stage_edge<KP>(Xb, srcS, nxt * 128, w, lane, A1);
            compute(A0, tile * 128);
        } else {
            if (nxt < ntiles) stage_edge<KP>(Xb, srcS, nxt * 128, w, lane, A0);
            compute(A1, tile * 128);
        }
        use0 = !use0;
        tile = nxt;
    }
}

// ---------------------------------------------------------------------------
// MFMA node-GEMM: act( (agg[n]/max(deg,1)) @ W + b ), dense rows, no atomics.
// MOUT: 1 = relu -> bf16 ws
//       2 = relu -> mu f32 (col<64) + zb bf16 (col<64), logvar f32 (col>=64)
//       3 = tanh -> f32 out
// ---------------------------------------------------------------------------
template<int KP, int NOUT, int MOUT>
__global__ __launch_bounds__(256, 2)
void k_node_mfma(const float* __restrict__ aggIn, const int* __restrict__ deg,
                 const float* __restrict__ W, const float* __restrict__ bias,
                 float* __restrict__ o0, float* __restrict__ o1,
                 unsigned short* __restrict__ bo, int M)
{
    constexpr int BLOCK_M = 128;
    constexpr int CH = KP / 8;
    constexpr int KSTEPS = KP / 32;
    constexpr int FM = 4;
    constexpr int FN = NOUT / 32;
    constexpr int BLK = 520;

    __shared__ unsigned short Alds[(BLOCK_M / 16) * KSTEPS * BLK];

    const int tid = threadIdx.x;
    const int lane = tid & 63;
    const int w = tid >> 6;
    const int lrow = lane & 15;
    const int lkg = lane >> 4;
    const int wrow0 = (w >> 1) * 64;
    const int cb0 = (w & 1) * (NOUT / 2);

    bf16x8 bfr[KSTEPS][FN];
    float eb[FN];
#pragma unroll
    for (int nf = 0; nf < FN; ++nf) {
        int col = cb0 + nf * 16 + lrow;
#pragma unroll
        for (int ks = 0; ks < KSTEPS; ++ks)
#pragma unroll
            for (int j = 0; j < 8; ++j) {
                int k = ks * 32 + lkg * 8 + j;
                bfr[ks][nf][j] = (__bf16)W[k * NOUT + col];
            }
        eb[nf] = bias[col];
    }

    const int ntiles = (M + BLOCK_M - 1) / BLOCK_M;
    for (int tile = blockIdx.x; tile < ntiles; tile += gridDim.x) {
        const int base = tile * BLOCK_M;
        __syncthreads();
        for (int t = tid; t < BLOCK_M * CH; t += 256) {
            int row = t / CH;
            int c = t % CH;
            int r = base + row;
            uint4 val = make_uint4(0, 0, 0, 0);
            if (r < M) {
                int dg = deg[r];
                float inv = 1.0f / (float)(dg > 1 ? dg : 1);
                const float4* p = (const float4*)(aggIn + (size_t)r * KP) + c * 2;
                float4 a = p[0], b = p[1];
                bf16x8 bv;
                bv[0] = (__bf16)(a.x * inv); bv[1] = (__bf16)(a.y * inv);
                bv[2] = (__bf16)(a.z * inv); bv[3] = (__bf16)(a.w * inv);
                bv[4] = (__bf16)(b.x * inv); bv[5] = (__bf16)(b.y * inv);
                bv[6] = (__bf16)(b.z * inv); bv[7] = (__bf16)(b.w * inv);
                val = __builtin_bit_cast(uint4, bv);
            }
            int mb = row >> 4, lr = row & 15, ks = c >> 2, q = c & 3;
            int unit = (q * 16 + lr) ^ (q << 1);
            *(uint4*)&Alds[(mb * KSTEPS + ks) * BLK + unit * 8] = val;
        }
        __syncthreads();

        f32x4 acc[FM][FN];
#pragma unroll
        for (int mf = 0; mf < FM; ++mf)
#pragma unroll
            for (int nf = 0; nf < FN; ++nf)
                acc[mf][nf] = 0;

        const int runit = lane ^ (lkg << 1);
#pragma unroll
        for (int ks = 0; ks < KSTEPS; ++ks) {
            bf16x8 afr[FM];
#pragma unroll
            for (int mf = 0; mf < FM; ++mf) {
                int mb = (wrow0 >> 4) + mf;
                afr[mf] = *(const bf16x8*)&Alds[(mb * KSTEPS + ks) * BLK + runit * 8];
            }
#pragma unroll
            for (int mf = 0; mf < FM; ++mf)
#pragma unroll
                for (int nf = 0; nf < FN; ++nf)
                    acc[mf][nf] = __builtin_amdgcn_mfma_f32_16x16x32_bf16(
                        afr[mf], bfr[ks][nf], acc[mf][nf], 0, 0, 0);
        }

#pragma unroll
        for (int mf = 0; mf < FM; ++mf) {
#pragma unroll
            for (int reg = 0; reg < 4; ++reg) {
                int row = wrow0 + mf * 16 + lkg * 4 + reg;
                int r = base + row;
                if (r < M) {
#pragma unroll
                    for (int nf = 0; nf < FN; ++nf) {
                        int col = cb0 + nf * 16 + lrow;
                        float tv = acc[mf][nf][reg] + eb[nf];
                        if constexpr (MOUT == 1) {
                            bo[(size_t)r * NOUT + col] = f2bu(fmaxf(tv, 0.f));
                        } else if constexpr (MOUT == 2) {
                            float v = fmaxf(tv, 0.f);
                            if (col < 64) {
                                o0[(size_t)r * 64 + col] = v;        // mu
                                bo[(size_t)r * 64 + col] = f2bu(v);  // z
                            } else {
                                o1[(size_t)r * 64 + (col - 64)] = v; // logvar
                            }
                        } else {
                            o0[(size_t)r * NOUT + col] = tanhf(tv);
                        }
                    }
                }
            }
        }
    }
}

// ---------------------------------------------------------------------------
// pet from bf16 xb: 16 lanes/edge, 8 bf16 per lane, shuffle reduce
// ---------------------------------------------------------------------------
__global__ __launch_bounds__(256)
void k_pet(const unsigned short* __restrict__ xb, const int* __restrict__ ei,
           const float* __restrict__ ew, const float* __restrict__ etW,
           const float* __restrict__ etb, float* __restrict__ out, int E)
{
    const int lane = threadIdx.x & 63;
    const long wg = ((long)blockIdx.x * blockDim.x + threadIdx.x) >> 6;
    const long e = wg * 4 + (lane >> 4);
    const int l16 = lane & 15;
    if (e >= E) return;
    const int s = ei[e], d = ei[E + e];
    uint4 av = ((const uint4*)(xb + (size_t)s * 128))[l16];
    uint4 bv = ((const uint4*)(xb + (size_t)d * 128))[l16];
    bf16x8 a = __builtin_bit_cast(bf16x8, av);
    bf16x8 b = __builtin_bit_cast(bf16x8, bv);
    float4 w0 = ((const float4*)etW)[l16 * 2];
    float4 w1 = ((const float4*)etW)[l16 * 2 + 1];
    float acc = fabsf((float)a[0] - (float)b[0]) * w0.x
              + fabsf((float)a[1] - (float)b[1]) * w0.y
              + fabsf((float)a[2] - (float)b[2]) * w0.z
              + fabsf((float)a[3] - (float)b[3]) * w0.w
              + fabsf((float)a[4] - (float)b[4]) * w1.x
              + fabsf((float)a[5] - (float)b[5]) * w1.y
              + fabsf((float)a[6] - (float)b[6]) * w1.z
              + fabsf((float)a[7] - (float)b[7]) * w1.w;
    acc += __shfl_xor(acc, 8);
    acc += __shfl_xor(acc, 4);
    acc += __shfl_xor(acc, 2);
    acc += __shfl_xor(acc, 1);
    if (l16 == 0)
        out[e] = acc + ew[2 * e] * etW[128] + ew[2 * e + 1] * etW[129] + etb[0];
}

// ---------------------------------------------------------------------------
extern "C" void kernel_launch(void* const* d_in, const int* in_sizes, int n_in,
                              void* d_out, int out_size, void* d_ws, size_t ws_size,
                              hipStream_t stream) {
    const float* x   = (const float*)d_in[0];
    const int*   ei  = (const int*)d_in[1];
    const float* ew  = (const float*)d_in[2];
    const float* Wc1 = (const float*)d_in[3];
    const float* bc1 = (const float*)d_in[4];
    const float* W1  = (const float*)d_in[5];
    const float* b1  = (const float*)d_in[6];
    const float* Wc2 = (const float*)d_in[7];
    const float* bc2 = (const float*)d_in[8];
    const float* W2  = (const float*)d_in[9];
    const float* b2  = (const float*)d_in[10];
    const float* Wc3 = (const float*)d_in[11];
    const float* bc3 = (const float*)d_in[12];
    const float* W3  = (const float*)d_in[13];
    const float* b3  = (const float*)d_in[14];
    const float* Wc4 = (const float*)d_in[15];
    const float* bc4 = (const float*)d_in[16];
    const float* W4  = (const float*)d_in[17];
    const float* b4  = (const float*)d_in[18];
    const float* etW = (const float*)d_in[19];
    const float* etb = (const float*)d_in[20];

    float* out   = (float*)d_out;
    float* recon = out;                              // N x 128
    float* mu    = out + (size_t)NN * 128;           // N x 64
    float* lv    = mu + (size_t)NN * 64;             // N x 64
    float* pet   = lv + (size_t)NN * 64;             // E x 1

    char* wsp = (char*)d_ws;
    float* agg          = (float*)(wsp);                      // 25.6 MB
    unsigned short* xb  = (unsigned short*)(wsp + 25600000);  // 12.8 MB
    unsigned short* h1b = (unsigned short*)(wsp + 38400000);  // 12.8 MB
    unsigned short* zb  = (unsigned short*)(wsp + 51200000);  // 6.4 MB
    unsigned short* db  = (unsigned short*)(wsp + 57600000);  // 12.8 MB
    int* deg            = (int*)(wsp + 70400000);             // 0.2 MB
    int* cursor         = (int*)(wsp + 70600000);             // 0.2 MB
    int* srcS           = (int*)(wsp + 70800000);             // 3.2 MB
    int* dstS           = (int*)(wsp + 74000000);             // 3.2 MB
    float2* ewS         = (float2*)(wsp + 77200000);          // 6.4 MB

    const int E = NE, NV = NN;

    // ---- precompute: degree, scan, dst-sorted edge arrays, bf16 x
    hipMemsetAsync(deg, 0, NV * sizeof(int), stream);
    k_deg<<<(E + 255) / 256, 256, 0, stream>>>(ei, deg, E);
    k_scan<<<1, 256, 0, stream>>>(deg, cursor, NV);
    k_scatter<<<(E + 255) / 256, 256, 0, stream>>>(ei, ew, cursor, srcS, dstS, ewS, E);
    k_cvt<<<(800000 + 255) / 256, 256, 0, stream>>>(x, xb, 800000);

    // ---- conv1: xb -> h1b
    hipMemsetAsync(agg, 0, (size_t)NV * 128 * 4, stream);
    k_edge_mfma<128, 128><<<1280, 256, 0, stream>>>(xb, srcS, dstS, ewS, Wc1, bc1, agg, E);
    k_node_mfma<128, 128, 1><<<391, 256, 0, stream>>>(agg, deg, W1, b1,
                                                      nullptr, nullptr, h1b, NV);

    // ---- conv2: h1b -> (mu, logvar, zb)
    hipMemsetAsync(agg, 0, (size_t)NV * 128 * 4, stream);
    k_edge_mfma<128, 128><<<1280, 256, 0, stream>>>(h1b, srcS, dstS, ewS, Wc2, bc2, agg, E);
    k_node_mfma<128, 128, 2><<<391, 256, 0, stream>>>(agg, deg, W2, b2,
                                                      mu, lv, zb, NV);

    // ---- pet (bf16 xb)
    k_pet<<<50000, 256, 0, stream>>>(xb, ei, ew, etW, etb, pet, E);

    // ---- conv3: zb -> db
    hipMemsetAsync(agg, 0, (size_t)NV * 64 * 4, stream);
    k_edge_mfma<64, 64><<<1280, 256, 0, stream>>>(zb, srcS, dstS, ewS, Wc3, bc3, agg, E);
    k_node_mfma<64, 128, 1><<<391, 256, 0, stream>>>(agg, deg, W3, b3,
                                                     nullptr, nullptr, db, NV);

    // ---- conv4: db -> recon
    hipMemsetAsync(agg, 0, (size_t)NV * 128 * 4, stream);
    k_edge_mfma<128, 128><<<1280, 256, 0, stream>>>(db, srcS, dstS, ewS, Wc4, bc4, agg, E);
    k_node_mfma<128, 128, 3><<<391, 256, 0, stream>>>(agg, deg, W4, b4,
                                                      recon, nullptr, nullptr, NV);
}

// Round 7
// 563.215 us; speedup vs baseline: 10.4096x; 2.3972x over previous
//
#include <hip/hip_runtime.h>
#include <hip/hip_bf16.h>

#define NN 50000
#define NE 800000

typedef __bf16 bf16x8 __attribute__((ext_vector_type(8)));
typedef float f32x4 __attribute__((ext_vector_type(4)));

__device__ __forceinline__ unsigned short f2bu(float f) {
    return __builtin_bit_cast(unsigned short, (__bf16)f);
}
__device__ __forceinline__ float b2f(unsigned short u) {
    return (float)__builtin_bit_cast(__bf16, u);
}

// ---------------------------------------------------------------------------
// f32 -> bf16 convert (x -> xb), 8 elements per thread
// ---------------------------------------------------------------------------
__global__ void k_cvt(const float* __restrict__ x, unsigned short* __restrict__ xb, int n8) {
    int i = blockIdx.x * blockDim.x + threadIdx.x;
    if (i >= n8) return;
    float4 a = ((const float4*)x)[i * 2];
    float4 b = ((const float4*)x)[i * 2 + 1];
    bf16x8 v;
    v[0] = (__bf16)a.x; v[1] = (__bf16)a.y; v[2] = (__bf16)a.z; v[3] = (__bf16)a.w;
    v[4] = (__bf16)b.x; v[5] = (__bf16)b.y; v[6] = (__bf16)b.z; v[7] = (__bf16)b.w;
    ((uint4*)xb)[i] = __builtin_bit_cast(uint4, v);
}

// ---------------------------------------------------------------------------
// in-degree histogram over dst = ei[E..2E)
// ---------------------------------------------------------------------------
__global__ void k_deg(const int* __restrict__ ei, int* __restrict__ deg, int E) {
    int e = blockIdx.x * blockDim.x + threadIdx.x;
    if (e < E) atomicAdd(&deg[ei[E + e]], 1);
}

// ---------------------------------------------------------------------------
// exclusive prefix sum of deg -> cursor (single 256-thread block, n=50000)
// ---------------------------------------------------------------------------
__global__ void k_scan(const int* __restrict__ deg, int* __restrict__ cursor, int n) {
    __shared__ int part[256];
    const int t = threadIdx.x;
    const int CHUNK = (n + 255) / 256;
    const int lo = t * CHUNK;
    const int hi = (lo + CHUNK < n) ? lo + CHUNK : n;
    int s = 0;
    for (int i = lo; i < hi; ++i) s += deg[i];
    part[t] = s;
    __syncthreads();
    int val = s;
    for (int off = 1; off < 256; off <<= 1) {
        int y = (t >= off) ? part[t - off] : 0;
        __syncthreads();
        val += y;
        part[t] = val;
        __syncthreads();
    }
    int run = val - s;   // exclusive prefix at chunk start
    for (int i = lo; i < hi; ++i) { cursor[i] = run; run += deg[i]; }
}

// ---------------------------------------------------------------------------
// scatter edges into dst-sorted order using cursor (post: cursor[n]=segment end)
// ---------------------------------------------------------------------------
__global__ void k_scatter(const int* __restrict__ ei, const float* __restrict__ ew,
                          int* __restrict__ cursor, int* __restrict__ srcS,
                          float2* __restrict__ ewS, int E) {
    int e = blockIdx.x * blockDim.x + threadIdx.x;
    if (e >= E) return;
    int d = ei[E + e];
    int s = atomicAdd(&cursor[d], 1);
    srcS[s] = ei[e];
    ewS[s] = ((const float2*)ew)[e];
}

// ---------------------------------------------------------------------------
// Dense MFMA GEMM, bf16 input rows, W/bias f32 -> registers.
// Tile 128 x NOUT, 4 waves (2x2), A fragment-major in LDS (520-pad + swizzle,
// verified conflict-free in R5). Grid-stride over row tiles.
// MOUT: 0 = plain bf16 store (no bias/act)           -> bo
//       1 = relu -> bf16                             -> bo
//       2 = relu -> mu f32 (col<64) + z bf16 (col<64), logvar f32 (col>=64)
//       3 = tanh -> f32                              -> o0
// ---------------------------------------------------------------------------
template<int KP, int NOUT, int MOUT>
__global__ __launch_bounds__(256, 2)
void k_dense(const unsigned short* __restrict__ Xb, const float* __restrict__ W,
             const float* __restrict__ bias, float* __restrict__ o0,
             float* __restrict__ o1, unsigned short* __restrict__ bo, int M)
{
    constexpr int BLOCK_M = 128;
    constexpr int CH = KP / 8;
    constexpr int KSTEPS = KP / 32;
    constexpr int FM = 4;
    constexpr int FN = NOUT / 32;
    constexpr int BLK = 520;

    __shared__ unsigned short Alds[8 * KSTEPS * BLK];

    const int tid = threadIdx.x;
    const int lane = tid & 63;
    const int w = tid >> 6;
    const int lrow = lane & 15;
    const int lkg = lane >> 4;
    const int wrow0 = (w >> 1) * 64;
    const int cb0 = (w & 1) * (NOUT / 2);

    bf16x8 bfr[KSTEPS][FN];
    float eb[FN];
#pragma unroll
    for (int nf = 0; nf < FN; ++nf) {
        int col = cb0 + nf * 16 + lrow;
#pragma unroll
        for (int ks = 0; ks < KSTEPS; ++ks)
#pragma unroll
            for (int j = 0; j < 8; ++j) {
                int k = ks * 32 + lkg * 8 + j;
                bfr[ks][nf][j] = (__bf16)W[k * NOUT + col];
            }
        if constexpr (MOUT != 0) eb[nf] = bias[col];
        else eb[nf] = 0.f;
    }

    const int ntiles = (M + BLOCK_M - 1) / BLOCK_M;
    for (int tile = blockIdx.x; tile < ntiles; tile += gridDim.x) {
        const int base = tile * BLOCK_M;
        __syncthreads();
        for (int t = tid; t < BLOCK_M * CH; t += 256) {
            int row = t / CH;
            int c = t % CH;
            int r = base + row;
            uint4 val = make_uint4(0, 0, 0, 0);
            if (r < M) val = *((const uint4*)(Xb + (size_t)r * KP) + c);
            int mb = row >> 4, lr = row & 15, ks = c >> 2, q = c & 3;
            int unit = (q * 16 + lr) ^ (q << 1);
            *(uint4*)&Alds[(mb * KSTEPS + ks) * BLK + unit * 8] = val;
        }
        __syncthreads();

        f32x4 acc[FM][FN];
#pragma unroll
        for (int mf = 0; mf < FM; ++mf)
#pragma unroll
            for (int nf = 0; nf < FN; ++nf)
                acc[mf][nf] = 0;

        const int runit = lane ^ (lkg << 1);
#pragma unroll
        for (int ks = 0; ks < KSTEPS; ++ks) {
            bf16x8 afr[FM];
#pragma unroll
            for (int mf = 0; mf < FM; ++mf) {
                int mb = (wrow0 >> 4) + mf;
                afr[mf] = *(const bf16x8*)&Alds[(mb * KSTEPS + ks) * BLK + runit * 8];
            }
#pragma unroll
            for (int mf = 0; mf < FM; ++mf)
#pragma unroll
                for (int nf = 0; nf < FN; ++nf)
                    acc[mf][nf] = __builtin_amdgcn_mfma_f32_16x16x32_bf16(
                        afr[mf], bfr[ks][nf], acc[mf][nf], 0, 0, 0);
        }

#pragma unroll
        for (int mf = 0; mf < FM; ++mf) {
#pragma unroll
            for (int reg = 0; reg < 4; ++reg) {
                int row = wrow0 + mf * 16 + lkg * 4 + reg;
                int r = base + row;
                if (r < M) {
#pragma unroll
                    for (int nf = 0; nf < FN; ++nf) {
                        int col = cb0 + nf * 16 + lrow;
                        float tv = acc[mf][nf][reg] + eb[nf];
                        if constexpr (MOUT == 0) {
                            bo[(size_t)r * NOUT + col] = f2bu(tv);
                        } else if constexpr (MOUT == 1) {
                            bo[(size_t)r * NOUT + col] = f2bu(fmaxf(tv, 0.f));
                        } else if constexpr (MOUT == 2) {
                            float v = fmaxf(tv, 0.f);
                            if (col < 64) {
                                o0[(size_t)r * 64 + col] = v;        // mu
                                bo[(size_t)r * 64 + col] = f2bu(v);  // z
                            } else {
                                o1[(size_t)r * 64 + (col - 64)] = v; // logvar
                            }
                        } else {
                            o0[(size_t)r * NOUT + col] = tanhf(tv);
                        }
                    }
                }
            }
        }
    }
}

// ---------------------------------------------------------------------------
// Per-node segment gather-reduce (NO atomics):
//   mean[n] = (1/max(deg,1)) * sum_{e in seg(n)} relu(Y[srcS[e]] + ew@er + bc)
// One 64-lane team per node, VC=NOUT/64 cols per lane. srcS/ewS prefetched
// one edge ahead; Y rows are L2/L3-resident bf16.
// ---------------------------------------------------------------------------
template<int NOUT>
__global__ __launch_bounds__(256)
void k_agg(const unsigned short* __restrict__ Yb, const int* __restrict__ srcS,
           const float2* __restrict__ ewS, const float* __restrict__ er,
           const float* __restrict__ bc, const int* __restrict__ cursor,
           const int* __restrict__ deg, unsigned short* __restrict__ meanb, int NV)
{
    constexpr int VC = NOUT / 64;
    const int lane = threadIdx.x & 63;
    const int team = threadIdx.x >> 6;
    const int n = blockIdx.x * 4 + team;
    if (n >= NV) return;
    const int c0 = lane * VC;

    float e0[VC], e1[VC], bcv[VC], acc[VC];
#pragma unroll
    for (int v = 0; v < VC; ++v) {
        e0[v] = er[c0 + v];
        e1[v] = er[NOUT + c0 + v];
        bcv[v] = bc[c0 + v];
        acc[v] = 0.f;
    }

    const int len = deg[n];
    const int base = cursor[n] - len;   // k_scatter left cursor[n] at segment end
    int srcC = 0;
    float2 ewC = make_float2(0.f, 0.f);
    if (len > 0) { srcC = srcS[base]; ewC = ewS[base]; }

    for (int i = 0; i < len; ++i) {
        int srcN = srcC;
        float2 ewN = ewC;
        if (i + 1 < len) { srcN = srcS[base + i + 1]; ewN = ewS[base + i + 1]; }
        if constexpr (VC == 2) {
            unsigned int y = *(const unsigned int*)(Yb + (size_t)srcC * NOUT + c0);
            float y0 = b2f((unsigned short)(y & 0xffff));
            float y1 = b2f((unsigned short)(y >> 16));
            acc[0] += fmaxf(y0 + ewC.x * e0[0] + ewC.y * e1[0] + bcv[0], 0.f);
            acc[1] += fmaxf(y1 + ewC.x * e0[1] + ewC.y * e1[1] + bcv[1], 0.f);
        } else {
            float y0 = b2f(Yb[(size_t)srcC * NOUT + c0]);
            acc[0] += fmaxf(y0 + ewC.x * e0[0] + ewC.y * e1[0] + bcv[0], 0.f);
        }
        srcC = srcN;
        ewC = ewN;
    }

    const float inv = 1.f / (float)(len > 1 ? len : 1);
    if constexpr (VC == 2) {
        unsigned int o = (unsigned int)f2bu(acc[0] * inv)
                       | ((unsigned int)f2bu(acc[1] * inv) << 16);
        *(unsigned int*)(meanb + (size_t)n * NOUT + c0) = o;
    } else {
        meanb[(size_t)n * NOUT + c0] = f2bu(acc[0] * inv);
    }
}

// ---------------------------------------------------------------------------
// pet from bf16 xb: 16 lanes/edge, 8 bf16 per lane, shuffle reduce
// ---------------------------------------------------------------------------
__global__ __launch_bounds__(256)
void k_pet(const unsigned short* __restrict__ xb, const int* __restrict__ ei,
           const float* __restrict__ ew, const float* __restrict__ etW,
           const float* __restrict__ etb, float* __restrict__ out, int E)
{
    const int lane = threadIdx.x & 63;
    const long wg = ((long)blockIdx.x * blockDim.x + threadIdx.x) >> 6;
    const long e = wg * 4 + (lane >> 4);
    const int l16 = lane & 15;
    if (e >= E) return;
    const int s = ei[e], d = ei[E + e];
    uint4 av = ((const uint4*)(xb + (size_t)s * 128))[l16];
    uint4 bv = ((const uint4*)(xb + (size_t)d * 128))[l16];
    bf16x8 a = __builtin_bit_cast(bf16x8, av);
    bf16x8 b = __builtin_bit_cast(bf16x8, bv);
    float4 w0 = ((const float4*)etW)[l16 * 2];
    float4 w1 = ((const float4*)etW)[l16 * 2 + 1];
    float acc = fabsf((float)a[0] - (float)b[0]) * w0.x
              + fabsf((float)a[1] - (float)b[1]) * w0.y
              + fabsf((float)a[2] - (float)b[2]) * w0.z
              + fabsf((float)a[3] - (float)b[3]) * w0.w
              + fabsf((float)a[4] - (float)b[4]) * w1.x
              + fabsf((float)a[5] - (float)b[5]) * w1.y
              + fabsf((float)a[6] - (float)b[6]) * w1.z
              + fabsf((float)a[7] - (float)b[7]) * w1.w;
    acc += __shfl_xor(acc, 8);
    acc += __shfl_xor(acc, 4);
    acc += __shfl_xor(acc, 2);
    acc += __shfl_xor(acc, 1);
    if (l16 == 0)
        out[e] = acc + ew[2 * e] * etW[128] + ew[2 * e + 1] * etW[129] + etb[0];
}

// ---------------------------------------------------------------------------
extern "C" void kernel_launch(void* const* d_in, const int* in_sizes, int n_in,
                              void* d_out, int out_size, void* d_ws, size_t ws_size,
                              hipStream_t stream) {
    const float* x   = (const float*)d_in[0];
    const int*   ei  = (const int*)d_in[1];
    const float* ew  = (const float*)d_in[2];
    const float* Wc1 = (const float*)d_in[3];
    const float* bc1 = (const float*)d_in[4];
    const float* W1  = (const float*)d_in[5];
    const float* b1  = (const float*)d_in[6];
    const float* Wc2 = (const float*)d_in[7];
    const float* bc2 = (const float*)d_in[8];
    const float* W2  = (const float*)d_in[9];
    const float* b2  = (const float*)d_in[10];
    const float* Wc3 = (const float*)d_in[11];
    const float* bc3 = (const float*)d_in[12];
    const float* W3  = (const float*)d_in[13];
    const float* b3  = (const float*)d_in[14];
    const float* Wc4 = (const float*)d_in[15];
    const float* bc4 = (const float*)d_in[16];
    const float* W4  = (const float*)d_in[17];
    const float* b4  = (const float*)d_in[18];
    const float* etW = (const float*)d_in[19];
    const float* etb = (const float*)d_in[20];

    float* out   = (float*)d_out;
    float* recon = out;                              // N x 128
    float* mu    = out + (size_t)NN * 128;           // N x 64
    float* lv    = mu + (size_t)NN * 64;             // N x 64
    float* pet   = lv + (size_t)NN * 64;             // E x 1

    char* wsp = (char*)d_ws;
    unsigned short* xb  = (unsigned short*)(wsp);              // 12.8 MB
    unsigned short* Yb  = (unsigned short*)(wsp + 12800000);   // 12.8 MB (scratch Y)
    unsigned short* ab  = (unsigned short*)(wsp + 25600000);   // 12.8 MB (scratch mean)
    unsigned short* h1b = (unsigned short*)(wsp + 38400000);   // 12.8 MB
    unsigned short* zb  = (unsigned short*)(wsp + 51200000);   // 6.4 MB
    unsigned short* db  = (unsigned short*)(wsp + 57600000);   // 12.8 MB
    int* deg            = (int*)(wsp + 70400000);              // 0.2 MB
    int* cursor         = (int*)(wsp + 70600000);              // 0.2 MB
    int* srcS           = (int*)(wsp + 70800000);              // 3.2 MB
    float2* ewS         = (float2*)(wsp + 74000000);           // 6.4 MB

    const int E = NE, NV = NN;

    // ---- precompute: degree, scan, dst-sorted (srcS, ewS), bf16 x
    hipMemsetAsync(deg, 0, NV * sizeof(int), stream);
    k_deg<<<(E + 255) / 256, 256, 0, stream>>>(ei, deg, E);
    k_scan<<<1, 256, 0, stream>>>(deg, cursor, NV);
    k_scatter<<<(E + 255) / 256, 256, 0, stream>>>(ei, ew, cursor, srcS, ewS, E);
    k_cvt<<<(800000 + 255) / 256, 256, 0, stream>>>(x, xb, 800000);

    // ---- conv1: Y1 = xb@Wc1 ; mean ; h1 = relu(mean@W1+b1)
    k_dense<128, 128, 0><<<391, 256, 0, stream>>>(xb, Wc1, nullptr,
                                                  nullptr, nullptr, Yb, NV);
    k_agg<128><<<12500, 256, 0, stream>>>(Yb, srcS, ewS, Wc1 + 128 * 128, bc1,
                                          cursor, deg, ab, NV);
    k_dense<128, 128, 1><<<391, 256, 0, stream>>>(ab, W1, b1,
                                                  nullptr, nullptr, h1b, NV);

    // ---- conv2: Y2 = h1@Wc2 ; mean ; (mu, logvar, z) = relu(mean@W2+b2)
    k_dense<128, 128, 0><<<391, 256, 0, stream>>>(h1b, Wc2, nullptr,
                                                  nullptr, nullptr, Yb, NV);
    k_agg<128><<<12500, 256, 0, stream>>>(Yb, srcS, ewS, Wc2 + 128 * 128, bc2,
                                          cursor, deg, ab, NV);
    k_dense<128, 128, 2><<<391, 256, 0, stream>>>(ab, W2, b2,
                                                  mu, lv, zb, NV);

    // ---- pet (bf16 xb)
    k_pet<<<50000, 256, 0, stream>>>(xb, ei, ew, etW, etb, pet, E);

    // ---- conv3: Y3 = zb@Wc3 ; mean ; d = relu(mean@W3+b3)
    k_dense<64, 64, 0><<<391, 256, 0, stream>>>(zb, Wc3, nullptr,
                                                nullptr, nullptr, Yb, NV);
    k_agg<64><<<12500, 256, 0, stream>>>(Yb, srcS, ewS, Wc3 + 64 * 64, bc3,
                                         cursor, deg, ab, NV);
    k_dense<64, 128, 1><<<391, 256, 0, stream>>>(ab, W3, b3,
                                                 nullptr, nullptr, db, NV);

    // ---- conv4: Y4 = db@Wc4 ; mean ; recon = tanh(mean@W4+b4)
    k_dense<128, 128, 0><<<391, 256, 0, stream>>>(db, Wc4, nullptr,
                                                  nullptr, nullptr, Yb, NV);
    k_agg<128><<<12500, 256, 0, stream>>>(Yb, srcS, ewS, Wc4 + 128 * 128, bc4,
                                          cursor, deg, ab, NV);
    k_dense<128, 128, 3><<<391, 256, 0, stream>>>(ab, W4, b4,
                                                  recon, nullptr, nullptr, NV);
}

// Round 8
// 497.295 us; speedup vs baseline: 11.7894x; 1.1326x over previous
//
#include <hip/hip_runtime.h>
#include <hip/hip_bf16.h>

#define NN 50000
#define NE 800000

typedef __bf16 bf16x8 __attribute__((ext_vector_type(8)));
typedef float f32x4 __attribute__((ext_vector_type(4)));

__device__ __forceinline__ unsigned short f2bu(float f) {
    return __builtin_bit_cast(unsigned short, (__bf16)f);
}
__device__ __forceinline__ float b2f(unsigned short u) {
    return (float)__builtin_bit_cast(__bf16, u);
}

// ---------------------------------------------------------------------------
// f32 -> bf16 convert (x -> xb), 8 elements per thread
// ---------------------------------------------------------------------------
__global__ void k_cvt(const float* __restrict__ x, unsigned short* __restrict__ xb, int n8) {
    int i = blockIdx.x * blockDim.x + threadIdx.x;
    if (i >= n8) return;
    float4 a = ((const float4*)x)[i * 2];
    float4 b = ((const float4*)x)[i * 2 + 1];
    bf16x8 v;
    v[0] = (__bf16)a.x; v[1] = (__bf16)a.y; v[2] = (__bf16)a.z; v[3] = (__bf16)a.w;
    v[4] = (__bf16)b.x; v[5] = (__bf16)b.y; v[6] = (__bf16)b.z; v[7] = (__bf16)b.w;
    ((uint4*)xb)[i] = __builtin_bit_cast(uint4, v);
}

// ---------------------------------------------------------------------------
// in-degree histogram over dst = ei[E..2E)
// ---------------------------------------------------------------------------
__global__ void k_deg(const int* __restrict__ ei, int* __restrict__ deg, int E) {
    int e = blockIdx.x * blockDim.x + threadIdx.x;
    if (e < E) atomicAdd(&deg[ei[E + e]], 1);
}

// ---------------------------------------------------------------------------
// Hierarchical exclusive scan of deg[0..n) -> cursor, 256 blocks.
// scan1: per-block chunk sum -> part[b]
// scan2: 1-block exclusive scan of part[256]
// scan3: per-chunk thread-per-element scan + part offset -> cursor
// chunk = ceil(n/256) = 196 <= 256 (one element per thread)
// ---------------------------------------------------------------------------
__global__ __launch_bounds__(256)
void k_scan1(const int* __restrict__ deg, int* __restrict__ part, int n) {
    const int b = blockIdx.x, t = threadIdx.x;
    const int chunk = (n + gridDim.x - 1) / gridDim.x;
    const int lo = b * chunk;
    const int cnt = min(chunk, n - lo);
    int v = (t < cnt) ? deg[lo + t] : 0;
    v += __shfl_xor(v, 1); v += __shfl_xor(v, 2); v += __shfl_xor(v, 4);
    v += __shfl_xor(v, 8); v += __shfl_xor(v, 16); v += __shfl_xor(v, 32);
    __shared__ int red[4];
    if ((t & 63) == 0) red[t >> 6] = v;
    __syncthreads();
    if (t == 0) part[b] = red[0] + red[1] + red[2] + red[3];
}

__global__ __launch_bounds__(256)
void k_scan2(int* __restrict__ part) {
    __shared__ int tmp[256];
    const int t = threadIdx.x;
    const int v = part[t];
    tmp[t] = v;
    __syncthreads();
    int val = v;
    for (int off = 1; off < 256; off <<= 1) {
        int y = (t >= off) ? tmp[t - off] : 0;
        __syncthreads();
        val += y;
        tmp[t] = val;
        __syncthreads();
    }
    part[t] = val - v;   // exclusive
}

__global__ __launch_bounds__(256)
void k_scan3(const int* __restrict__ deg, const int* __restrict__ part,
             int* __restrict__ cursor, int n) {
    __shared__ int tmp[256];
    const int b = blockIdx.x, t = threadIdx.x;
    const int chunk = (n + gridDim.x - 1) / gridDim.x;
    const int lo = b * chunk;
    const int cnt = min(chunk, n - lo);
    const int v = (t < cnt) ? deg[lo + t] : 0;
    tmp[t] = v;
    __syncthreads();
    int val = v;
    for (int off = 1; off < 256; off <<= 1) {
        int y = (t >= off) ? tmp[t - off] : 0;
        __syncthreads();
        val += y;
        tmp[t] = val;
        __syncthreads();
    }
    if (t < cnt) cursor[lo + t] = part[b] + val - v;   // exclusive + block offset
}

// ---------------------------------------------------------------------------
// scatter edges into dst-sorted order using cursor (post: cursor[n]=segment end)
// ---------------------------------------------------------------------------
__global__ void k_scatter(const int* __restrict__ ei, const float* __restrict__ ew,
                          int* __restrict__ cursor, int* __restrict__ srcS,
                          float2* __restrict__ ewS, int E) {
    int e = blockIdx.x * blockDim.x + threadIdx.x;
    if (e >= E) return;
    int d = ei[E + e];
    int s = atomicAdd(&cursor[d], 1);
    srcS[s] = ei[e];
    ewS[s] = ((const float2*)ew)[e];
}

// ---------------------------------------------------------------------------
// Dense MFMA GEMM, bf16 input rows, W/bias f32 -> registers.
// Tile 128 x NOUT, 4 waves (2x2), A fragment-major in LDS (520-pad + swizzle).
// MOUT: 0 = plain bf16 store; 1 = relu->bf16; 2 = relu->mu f32 + z bf16 /
//       logvar f32; 3 = tanh->f32
// ---------------------------------------------------------------------------
template<int KP, int NOUT, int MOUT>
__global__ __launch_bounds__(256, 2)
void k_dense(const unsigned short* __restrict__ Xb, const float* __restrict__ W,
             const float* __restrict__ bias, float* __restrict__ o0,
             float* __restrict__ o1, unsigned short* __restrict__ bo, int M)
{
    constexpr int BLOCK_M = 128;
    constexpr int CH = KP / 8;
    constexpr int KSTEPS = KP / 32;
    constexpr int FM = 4;
    constexpr int FN = NOUT / 32;
    constexpr int BLK = 520;

    __shared__ unsigned short Alds[8 * KSTEPS * BLK];

    const int tid = threadIdx.x;
    const int lane = tid & 63;
    const int w = tid >> 6;
    const int lrow = lane & 15;
    const int lkg = lane >> 4;
    const int wrow0 = (w >> 1) * 64;
    const int cb0 = (w & 1) * (NOUT / 2);

    bf16x8 bfr[KSTEPS][FN];
    float eb[FN];
#pragma unroll
    for (int nf = 0; nf < FN; ++nf) {
        int col = cb0 + nf * 16 + lrow;
#pragma unroll
        for (int ks = 0; ks < KSTEPS; ++ks)
#pragma unroll
            for (int j = 0; j < 8; ++j) {
                int k = ks * 32 + lkg * 8 + j;
                bfr[ks][nf][j] = (__bf16)W[k * NOUT + col];
            }
        if constexpr (MOUT != 0) eb[nf] = bias[col];
        else eb[nf] = 0.f;
    }

    const int ntiles = (M + BLOCK_M - 1) / BLOCK_M;
    for (int tile = blockIdx.x; tile < ntiles; tile += gridDim.x) {
        const int base = tile * BLOCK_M;
        __syncthreads();
        for (int t = tid; t < BLOCK_M * CH; t += 256) {
            int row = t / CH;
            int c = t % CH;
            int r = base + row;
            uint4 val = make_uint4(0, 0, 0, 0);
            if (r < M) val = *((const uint4*)(Xb + (size_t)r * KP) + c);
            int mb = row >> 4, lr = row & 15, ks = c >> 2, q = c & 3;
            int unit = (q * 16 + lr) ^ (q << 1);
            *(uint4*)&Alds[(mb * KSTEPS + ks) * BLK + unit * 8] = val;
        }
        __syncthreads();

        f32x4 acc[FM][FN];
#pragma unroll
        for (int mf = 0; mf < FM; ++mf)
#pragma unroll
            for (int nf = 0; nf < FN; ++nf)
                acc[mf][nf] = 0;

        const int runit = lane ^ (lkg << 1);
#pragma unroll
        for (int ks = 0; ks < KSTEPS; ++ks) {
            bf16x8 afr[FM];
#pragma unroll
            for (int mf = 0; mf < FM; ++mf) {
                int mb = (wrow0 >> 4) + mf;
                afr[mf] = *(const bf16x8*)&Alds[(mb * KSTEPS + ks) * BLK + runit * 8];
            }
#pragma unroll
            for (int mf = 0; mf < FM; ++mf)
#pragma unroll
                for (int nf = 0; nf < FN; ++nf)
                    acc[mf][nf] = __builtin_amdgcn_mfma_f32_16x16x32_bf16(
                        afr[mf], bfr[ks][nf], acc[mf][nf], 0, 0, 0);
        }

#pragma unroll
        for (int mf = 0; mf < FM; ++mf) {
#pragma unroll
            for (int reg = 0; reg < 4; ++reg) {
                int row = wrow0 + mf * 16 + lkg * 4 + reg;
                int r = base + row;
                if (r < M) {
#pragma unroll
                    for (int nf = 0; nf < FN; ++nf) {
                        int col = cb0 + nf * 16 + lrow;
                        float tv = acc[mf][nf][reg] + eb[nf];
                        if constexpr (MOUT == 0) {
                            bo[(size_t)r * NOUT + col] = f2bu(tv);
                        } else if constexpr (MOUT == 1) {
                            bo[(size_t)r * NOUT + col] = f2bu(fmaxf(tv, 0.f));
                        } else if constexpr (MOUT == 2) {
                            float v = fmaxf(tv, 0.f);
                            if (col < 64) {
                                o0[(size_t)r * 64 + col] = v;        // mu
                                bo[(size_t)r * 64 + col] = f2bu(v);  // z
                            } else {
                                o1[(size_t)r * 64 + (col - 64)] = v; // logvar
                            }
                        } else {
                            o0[(size_t)r * NOUT + col] = tanhf(tv);
                        }
                    }
                }
            }
        }
    }
}

// ---------------------------------------------------------------------------
// Per-node segment gather-reduce (NO atomics):
//   mean[n] = (1/max(deg,1)) * sum_{e in seg(n)} relu(Y[srcS[e]] + ew@er + bc)
// One 64-lane team per node, VC=NOUT/64 cols per lane, prefetch-1.
// ---------------------------------------------------------------------------
template<int NOUT>
__global__ __launch_bounds__(256)
void k_agg(const unsigned short* __restrict__ Yb, const int* __restrict__ srcS,
           const float2* __restrict__ ewS, const float* __restrict__ er,
           const float* __restrict__ bc, const int* __restrict__ cursor,
           const int* __restrict__ deg, unsigned short* __restrict__ meanb, int NV)
{
    constexpr int VC = NOUT / 64;
    const int lane = threadIdx.x & 63;
    const int team = threadIdx.x >> 6;
    const int n = blockIdx.x * 4 + team;
    if (n >= NV) return;
    const int c0 = lane * VC;

    float e0[VC], e1[VC], bcv[VC], acc[VC];
#pragma unroll
    for (int v = 0; v < VC; ++v) {
        e0[v] = er[c0 + v];
        e1[v] = er[NOUT + c0 + v];
        bcv[v] = bc[c0 + v];
        acc[v] = 0.f;
    }

    const int len = deg[n];
    const int base = cursor[n] - len;   // k_scatter left cursor[n] at segment end
    int srcC = 0;
    float2 ewC = make_float2(0.f, 0.f);
    if (len > 0) { srcC = srcS[base]; ewC = ewS[base]; }

    for (int i = 0; i < len; ++i) {
        int srcN = srcC;
        float2 ewN = ewC;
        if (i + 1 < len) { srcN = srcS[base + i + 1]; ewN = ewS[base + i + 1]; }
        if constexpr (VC == 2) {
            unsigned int y = *(const unsigned int*)(Yb + (size_t)srcC * NOUT + c0);
            float y0 = b2f((unsigned short)(y & 0xffff));
            float y1 = b2f((unsigned short)(y >> 16));
            acc[0] += fmaxf(y0 + ewC.x * e0[0] + ewC.y * e1[0] + bcv[0], 0.f);
            acc[1] += fmaxf(y1 + ewC.x * e0[1] + ewC.y * e1[1] + bcv[1], 0.f);
        } else {
            float y0 = b2f(Yb[(size_t)srcC * NOUT + c0]);
            acc[0] += fmaxf(y0 + ewC.x * e0[0] + ewC.y * e1[0] + bcv[0], 0.f);
        }
        srcC = srcN;
        ewC = ewN;
    }

    const float inv = 1.f / (float)(len > 1 ? len : 1);
    if constexpr (VC == 2) {
        unsigned int o = (unsigned int)f2bu(acc[0] * inv)
                       | ((unsigned int)f2bu(acc[1] * inv) << 16);
        *(unsigned int*)(meanb + (size_t)n * NOUT + c0) = o;
    } else {
        meanb[(size_t)n * NOUT + c0] = f2bu(acc[0] * inv);
    }
}

// ---------------------------------------------------------------------------
// pet from bf16 xb: 16 lanes/edge, 8 bf16 per lane, shuffle reduce
// ---------------------------------------------------------------------------
__global__ __launch_bounds__(256)
void k_pet(const unsigned short* __restrict__ xb, const int* __restrict__ ei,
           const float* __restrict__ ew, const float* __restrict__ etW,
           const float* __restrict__ etb, float* __restrict__ out, int E)
{
    const int lane = threadIdx.x & 63;
    const long wg = ((long)blockIdx.x * blockDim.x + threadIdx.x) >> 6;
    const long e = wg * 4 + (lane >> 4);
    const int l16 = lane & 15;
    if (e >= E) return;
    const int s = ei[e], d = ei[E + e];
    uint4 av = ((const uint4*)(xb + (size_t)s * 128))[l16];
    uint4 bv = ((const uint4*)(xb + (size_t)d * 128))[l16];
    bf16x8 a = __builtin_bit_cast(bf16x8, av);
    bf16x8 b = __builtin_bit_cast(bf16x8, bv);
    float4 w0 = ((const float4*)etW)[l16 * 2];
    float4 w1 = ((const float4*)etW)[l16 * 2 + 1];
    float acc = fabsf((float)a[0] - (float)b[0]) * w0.x
              + fabsf((float)a[1] - (float)b[1]) * w0.y
              + fabsf((float)a[2] - (float)b[2]) * w0.z
              + fabsf((float)a[3] - (float)b[3]) * w0.w
              + fabsf((float)a[4] - (float)b[4]) * w1.x
              + fabsf((float)a[5] - (float)b[5]) * w1.y
              + fabsf((float)a[6] - (float)b[6]) * w1.z
              + fabsf((float)a[7] - (float)b[7]) * w1.w;
    acc += __shfl_xor(acc, 8);
    acc += __shfl_xor(acc, 4);
    acc += __shfl_xor(acc, 2);
    acc += __shfl_xor(acc, 1);
    if (l16 == 0)
        out[e] = acc + ew[2 * e] * etW[128] + ew[2 * e + 1] * etW[129] + etb[0];
}

// ---------------------------------------------------------------------------
extern "C" void kernel_launch(void* const* d_in, const int* in_sizes, int n_in,
                              void* d_out, int out_size, void* d_ws, size_t ws_size,
                              hipStream_t stream) {
    const float* x   = (const float*)d_in[0];
    const int*   ei  = (const int*)d_in[1];
    const float* ew  = (const float*)d_in[2];
    const float* Wc1 = (const float*)d_in[3];
    const float* bc1 = (const float*)d_in[4];
    const float* W1  = (const float*)d_in[5];
    const float* b1  = (const float*)d_in[6];
    const float* Wc2 = (const float*)d_in[7];
    const float* bc2 = (const float*)d_in[8];
    const float* W2  = (const float*)d_in[9];
    const float* b2  = (const float*)d_in[10];
    const float* Wc3 = (const float*)d_in[11];
    const float* bc3 = (const float*)d_in[12];
    const float* W3  = (const float*)d_in[13];
    const float* b3  = (const float*)d_in[14];
    const float* Wc4 = (const float*)d_in[15];
    const float* bc4 = (const float*)d_in[16];
    const float* W4  = (const float*)d_in[17];
    const float* b4  = (const float*)d_in[18];
    const float* etW = (const float*)d_in[19];
    const float* etb = (const float*)d_in[20];

    float* out   = (float*)d_out;
    float* recon = out;                              // N x 128
    float* mu    = out + (size_t)NN * 128;           // N x 64
    float* lv    = mu + (size_t)NN * 64;             // N x 64
    float* pet   = lv + (size_t)NN * 64;             // E x 1

    char* wsp = (char*)d_ws;
    unsigned short* xb  = (unsigned short*)(wsp);              // 12.8 MB
    unsigned short* Yb  = (unsigned short*)(wsp + 12800000);   // 12.8 MB (scratch Y)
    unsigned short* ab  = (unsigned short*)(wsp + 25600000);   // 12.8 MB (scratch mean)
    unsigned short* h1b = (unsigned short*)(wsp + 38400000);   // 12.8 MB
    unsigned short* zb  = (unsigned short*)(wsp + 51200000);   // 6.4 MB
    unsigned short* db  = (unsigned short*)(wsp + 57600000);   // 12.8 MB
    int* deg            = (int*)(wsp + 70400000);              // 0.2 MB
    int* cursor         = (int*)(wsp + 70600000);              // 0.2 MB
    int* srcS           = (int*)(wsp + 70800000);              // 3.2 MB
    float2* ewS         = (float2*)(wsp + 74000000);           // 6.4 MB
    int* part           = (int*)(wsp + 80400000);              // 1 KB

    const int E = NE, NV = NN;

    // ---- precompute: degree, hierarchical scan, dst-sorted (srcS, ewS), bf16 x
    hipMemsetAsync(deg, 0, NV * sizeof(int), stream);
    k_deg<<<(E + 255) / 256, 256, 0, stream>>>(ei, deg, E);
    k_scan1<<<256, 256, 0, stream>>>(deg, part, NV);
    k_scan2<<<1, 256, 0, stream>>>(part);
    k_scan3<<<256, 256, 0, stream>>>(deg, part, cursor, NV);
    k_scatter<<<(E + 255) / 256, 256, 0, stream>>>(ei, ew, cursor, srcS, ewS, E);
    k_cvt<<<(800000 + 255) / 256, 256, 0, stream>>>(x, xb, 800000);

    // ---- conv1: Y1 = xb@Wc1 ; mean ; h1 = relu(mean@W1+b1)
    k_dense<128, 128, 0><<<391, 256, 0, stream>>>(xb, Wc1, nullptr,
                                                  nullptr, nullptr, Yb, NV);
    k_agg<128><<<12500, 256, 0, stream>>>(Yb, srcS, ewS, Wc1 + 128 * 128, bc1,
                                          cursor, deg, ab, NV);
    k_dense<128, 128, 1><<<391, 256, 0, stream>>>(ab, W1, b1,
                                                  nullptr, nullptr, h1b, NV);

    // ---- conv2: Y2 = h1@Wc2 ; mean ; (mu, logvar, z) = relu(mean@W2+b2)
    k_dense<128, 128, 0><<<391, 256, 0, stream>>>(h1b, Wc2, nullptr,
                                                  nullptr, nullptr, Yb, NV);
    k_agg<128><<<12500, 256, 0, stream>>>(Yb, srcS, ewS, Wc2 + 128 * 128, bc2,
                                          cursor, deg, ab, NV);
    k_dense<128, 128, 2><<<391, 256, 0, stream>>>(ab, W2, b2,
                                                  mu, lv, zb, NV);

    // ---- pet (bf16 xb)
    k_pet<<<50000, 256, 0, stream>>>(xb, ei, ew, etW, etb, pet, E);

    // ---- conv3: Y3 = zb@Wc3 ; mean ; d = relu(mean@W3+b3)
    k_dense<64, 64, 0><<<391, 256, 0, stream>>>(zb, Wc3, nullptr,
                                                nullptr, nullptr, Yb, NV);
    k_agg<64><<<12500, 256, 0, stream>>>(Yb, srcS, ewS, Wc3 + 64 * 64, bc3,
                                         cursor, deg, ab, NV);
    k_dense<64, 128, 1><<<391, 256, 0, stream>>>(ab, W3, b3,
                                                 nullptr, nullptr, db, NV);

    // ---- conv4: Y4 = db@Wc4 ; mean ; recon = tanh(mean@W4+b4)
    k_dense<128, 128, 0><<<391, 256, 0, stream>>>(db, Wc4, nullptr,
                                                  nullptr, nullptr, Yb, NV);
    k_agg<128><<<12500, 256, 0, stream>>>(Yb, srcS, ewS, Wc4 + 128 * 128, bc4,
                                          cursor, deg, ab, NV);
    k_dense<128, 128, 3><<<391, 256, 0, stream>>>(ab, W4, b4,
                                                  recon, nullptr, nullptr, NV);
}

// Round 9
// 485.364 us; speedup vs baseline: 12.0792x; 1.0246x over previous
//
#include <hip/hip_runtime.h>
#include <hip/hip_bf16.h>

#define NN 50000
#define NE 800000

typedef __bf16 bf16x8 __attribute__((ext_vector_type(8)));
typedef float f32x4 __attribute__((ext_vector_type(4)));

__device__ __forceinline__ unsigned short f2bu(float f) {
    return __builtin_bit_cast(unsigned short, (__bf16)f);
}
__device__ __forceinline__ float b2f(unsigned short u) {
    return (float)__builtin_bit_cast(__bf16, u);
}

// ---------------------------------------------------------------------------
// f32 -> bf16 convert (x -> xb), 8 elements per thread
// ---------------------------------------------------------------------------
__global__ void k_cvt(const float* __restrict__ x, unsigned short* __restrict__ xb, int n8) {
    int i = blockIdx.x * blockDim.x + threadIdx.x;
    if (i >= n8) return;
    float4 a = ((const float4*)x)[i * 2];
    float4 b = ((const float4*)x)[i * 2 + 1];
    bf16x8 v;
    v[0] = (__bf16)a.x; v[1] = (__bf16)a.y; v[2] = (__bf16)a.z; v[3] = (__bf16)a.w;
    v[4] = (__bf16)b.x; v[5] = (__bf16)b.y; v[6] = (__bf16)b.z; v[7] = (__bf16)b.w;
    ((uint4*)xb)[i] = __builtin_bit_cast(uint4, v);
}

// ---------------------------------------------------------------------------
// in-degree histogram over dst = ei[E..2E)
// ---------------------------------------------------------------------------
__global__ void k_deg(const int* __restrict__ ei, int* __restrict__ deg, int E) {
    int e = blockIdx.x * blockDim.x + threadIdx.x;
    if (e < E) atomicAdd(&deg[ei[E + e]], 1);
}

// ---------------------------------------------------------------------------
// Hierarchical exclusive scan of deg[0..n) -> cursor, 256 blocks.
// ---------------------------------------------------------------------------
__global__ __launch_bounds__(256)
void k_scan1(const int* __restrict__ deg, int* __restrict__ part, int n) {
    const int b = blockIdx.x, t = threadIdx.x;
    const int chunk = (n + gridDim.x - 1) / gridDim.x;
    const int lo = b * chunk;
    const int cnt = min(chunk, n - lo);
    int v = (t < cnt) ? deg[lo + t] : 0;
    v += __shfl_xor(v, 1); v += __shfl_xor(v, 2); v += __shfl_xor(v, 4);
    v += __shfl_xor(v, 8); v += __shfl_xor(v, 16); v += __shfl_xor(v, 32);
    __shared__ int red[4];
    if ((t & 63) == 0) red[t >> 6] = v;
    __syncthreads();
    if (t == 0) part[b] = red[0] + red[1] + red[2] + red[3];
}

__global__ __launch_bounds__(256)
void k_scan2(int* __restrict__ part) {
    __shared__ int tmp[256];
    const int t = threadIdx.x;
    const int v = part[t];
    tmp[t] = v;
    __syncthreads();
    int val = v;
    for (int off = 1; off < 256; off <<= 1) {
        int y = (t >= off) ? tmp[t - off] : 0;
        __syncthreads();
        val += y;
        tmp[t] = val;
        __syncthreads();
    }
    part[t] = val - v;   // exclusive
}

__global__ __launch_bounds__(256)
void k_scan3(const int* __restrict__ deg, const int* __restrict__ part,
             int* __restrict__ cursor, int n) {
    __shared__ int tmp[256];
    const int b = blockIdx.x, t = threadIdx.x;
    const int chunk = (n + gridDim.x - 1) / gridDim.x;
    const int lo = b * chunk;
    const int cnt = min(chunk, n - lo);
    const int v = (t < cnt) ? deg[lo + t] : 0;
    tmp[t] = v;
    __syncthreads();
    int val = v;
    for (int off = 1; off < 256; off <<= 1) {
        int y = (t >= off) ? tmp[t - off] : 0;
        __syncthreads();
        val += y;
        tmp[t] = val;
        __syncthreads();
    }
    if (t < cnt) cursor[lo + t] = part[b] + val - v;   // exclusive + block offset
}

// ---------------------------------------------------------------------------
// scatter edges into dst-sorted order using cursor (post: cursor[n]=segment end)
// ---------------------------------------------------------------------------
__global__ void k_scatter(const int* __restrict__ ei, const float* __restrict__ ew,
                          int* __restrict__ cursor, int* __restrict__ srcS,
                          float2* __restrict__ ewS, int E) {
    int e = blockIdx.x * blockDim.x + threadIdx.x;
    if (e >= E) return;
    int d = ei[E + e];
    int s = atomicAdd(&cursor[d], 1);
    srcS[s] = ei[e];
    ewS[s] = ((const float2*)ew)[e];
}

// ---------------------------------------------------------------------------
// Dense MFMA GEMM, bf16 input rows, W/bias f32 -> registers.
// Tile 128 x NOUT, 4 waves (2x2), A fragment-major in LDS (520-pad + swizzle).
// MOUT: 0 = plain bf16 store; 1 = relu->bf16; 2 = relu->mu f32 + z bf16 /
//       logvar f32; 3 = tanh->f32
// ---------------------------------------------------------------------------
template<int KP, int NOUT, int MOUT>
__global__ __launch_bounds__(256, 2)
void k_dense(const unsigned short* __restrict__ Xb, const float* __restrict__ W,
             const float* __restrict__ bias, float* __restrict__ o0,
             float* __restrict__ o1, unsigned short* __restrict__ bo, int M)
{
    constexpr int BLOCK_M = 128;
    constexpr int CH = KP / 8;
    constexpr int KSTEPS = KP / 32;
    constexpr int FM = 4;
    constexpr int FN = NOUT / 32;
    constexpr int BLK = 520;

    __shared__ unsigned short Alds[8 * KSTEPS * BLK];

    const int tid = threadIdx.x;
    const int lane = tid & 63;
    const int w = tid >> 6;
    const int lrow = lane & 15;
    const int lkg = lane >> 4;
    const int wrow0 = (w >> 1) * 64;
    const int cb0 = (w & 1) * (NOUT / 2);

    bf16x8 bfr[KSTEPS][FN];
    float eb[FN];
#pragma unroll
    for (int nf = 0; nf < FN; ++nf) {
        int col = cb0 + nf * 16 + lrow;
#pragma unroll
        for (int ks = 0; ks < KSTEPS; ++ks)
#pragma unroll
            for (int j = 0; j < 8; ++j) {
                int k = ks * 32 + lkg * 8 + j;
                bfr[ks][nf][j] = (__bf16)W[k * NOUT + col];
            }
        if constexpr (MOUT != 0) eb[nf] = bias[col];
        else eb[nf] = 0.f;
    }

    const int ntiles = (M + BLOCK_M - 1) / BLOCK_M;
    for (int tile = blockIdx.x; tile < ntiles; tile += gridDim.x) {
        const int base = tile * BLOCK_M;
        __syncthreads();
        for (int t = tid; t < BLOCK_M * CH; t += 256) {
            int row = t / CH;
            int c = t % CH;
            int r = base + row;
            uint4 val = make_uint4(0, 0, 0, 0);
            if (r < M) val = *((const uint4*)(Xb + (size_t)r * KP) + c);
            int mb = row >> 4, lr = row & 15, ks = c >> 2, q = c & 3;
            int unit = (q * 16 + lr) ^ (q << 1);
            *(uint4*)&Alds[(mb * KSTEPS + ks) * BLK + unit * 8] = val;
        }
        __syncthreads();

        f32x4 acc[FM][FN];
#pragma unroll
        for (int mf = 0; mf < FM; ++mf)
#pragma unroll
            for (int nf = 0; nf < FN; ++nf)
                acc[mf][nf] = 0;

        const int runit = lane ^ (lkg << 1);
#pragma unroll
        for (int ks = 0; ks < KSTEPS; ++ks) {
            bf16x8 afr[FM];
#pragma unroll
            for (int mf = 0; mf < FM; ++mf) {
                int mb = (wrow0 >> 4) + mf;
                afr[mf] = *(const bf16x8*)&Alds[(mb * KSTEPS + ks) * BLK + runit * 8];
            }
#pragma unroll
            for (int mf = 0; mf < FM; ++mf)
#pragma unroll
                for (int nf = 0; nf < FN; ++nf)
                    acc[mf][nf] = __builtin_amdgcn_mfma_f32_16x16x32_bf16(
                        afr[mf], bfr[ks][nf], acc[mf][nf], 0, 0, 0);
        }

#pragma unroll
        for (int mf = 0; mf < FM; ++mf) {
#pragma unroll
            for (int reg = 0; reg < 4; ++reg) {
                int row = wrow0 + mf * 16 + lkg * 4 + reg;
                int r = base + row;
                if (r < M) {
#pragma unroll
                    for (int nf = 0; nf < FN; ++nf) {
                        int col = cb0 + nf * 16 + lrow;
                        float tv = acc[mf][nf][reg] + eb[nf];
                        if constexpr (MOUT == 0) {
                            bo[(size_t)r * NOUT + col] = f2bu(tv);
                        } else if constexpr (MOUT == 1) {
                            bo[(size_t)r * NOUT + col] = f2bu(fmaxf(tv, 0.f));
                        } else if constexpr (MOUT == 2) {
                            float v = fmaxf(tv, 0.f);
                            if (col < 64) {
                                o0[(size_t)r * 64 + col] = v;        // mu
                                bo[(size_t)r * 64 + col] = f2bu(v);  // z
                            } else {
                                o1[(size_t)r * 64 + (col - 64)] = v; // logvar
                            }
                        } else {
                            o0[(size_t)r * NOUT + col] = tanhf(tv);
                        }
                    }
                }
            }
        }
    }
}

// ---------------------------------------------------------------------------
// Per-node segment gather-reduce (NO atomics), 8-deep MLP batching:
//   mean[n] = (1/max(deg,1)) * sum_{e in seg(n)} relu(Y[srcS[e]] + ew@er + bc)
// One 64-lane team per node, VC=NOUT/64 cols per lane. Per 8-edge chunk:
// issue 8 srcS/ewS loads, then 8 Y-row loads (8 outstanding VMEM), then
// compute 8 — amortizes L2/L3 gather latency ~8x vs serial-dependent loop.
// ---------------------------------------------------------------------------
template<int NOUT>
__global__ __launch_bounds__(256)
void k_agg(const unsigned short* __restrict__ Yb, const int* __restrict__ srcS,
           const float2* __restrict__ ewS, const float* __restrict__ er,
           const float* __restrict__ bc, const int* __restrict__ cursor,
           const int* __restrict__ deg, unsigned short* __restrict__ meanb, int NV)
{
    constexpr int VC = NOUT / 64;
    constexpr int UF = 8;
    const int lane = threadIdx.x & 63;
    const int team = threadIdx.x >> 6;
    const int n = blockIdx.x * 4 + team;
    if (n >= NV) return;
    const int c0 = lane * VC;

    float e0[VC], e1[VC], bcv[VC], acc[VC];
#pragma unroll
    for (int v = 0; v < VC; ++v) {
        e0[v] = er[c0 + v];
        e1[v] = er[NOUT + c0 + v];
        bcv[v] = bc[c0 + v];
        acc[v] = 0.f;
    }

    const int len = deg[n];
    const int base = cursor[n] - len;   // k_scatter left cursor[n] at segment end

    for (int chunk = 0; chunk < len; chunk += UF) {
        const int m = len - chunk;      // wave-uniform
        int src[UF];
        float2 ewv[UF];
        unsigned int y2[UF];
        unsigned short y1[UF];
        // phase 1: indices + edge weights (uniform-address broadcast loads)
#pragma unroll
        for (int j = 0; j < UF; ++j) {
            if (j < m) {
                src[j] = srcS[base + chunk + j];
                ewv[j] = ewS[base + chunk + j];
            }
        }
        // phase 2: Y-row gathers — up to UF outstanding VMEM ops
#pragma unroll
        for (int j = 0; j < UF; ++j) {
            if (j < m) {
                if constexpr (VC == 2)
                    y2[j] = *(const unsigned int*)(Yb + (size_t)src[j] * NOUT + c0);
                else
                    y1[j] = Yb[(size_t)src[j] * NOUT + c0];
            }
        }
        // phase 3: compute
#pragma unroll
        for (int j = 0; j < UF; ++j) {
            if (j < m) {
                if constexpr (VC == 2) {
                    float ya = b2f((unsigned short)(y2[j] & 0xffff));
                    float yb = b2f((unsigned short)(y2[j] >> 16));
                    acc[0] += fmaxf(ya + ewv[j].x * e0[0] + ewv[j].y * e1[0] + bcv[0], 0.f);
                    acc[1] += fmaxf(yb + ewv[j].x * e0[1] + ewv[j].y * e1[1] + bcv[1], 0.f);
                } else {
                    float ya = b2f(y1[j]);
                    acc[0] += fmaxf(ya + ewv[j].x * e0[0] + ewv[j].y * e1[0] + bcv[0], 0.f);
                }
            }
        }
    }

    const float inv = 1.f / (float)(len > 1 ? len : 1);
    if constexpr (VC == 2) {
        unsigned int o = (unsigned int)f2bu(acc[0] * inv)
                       | ((unsigned int)f2bu(acc[1] * inv) << 16);
        *(unsigned int*)(meanb + (size_t)n * NOUT + c0) = o;
    } else {
        meanb[(size_t)n * NOUT + c0] = f2bu(acc[0] * inv);
    }
}

// ---------------------------------------------------------------------------
// pet from bf16 xb: 16 lanes/edge, 8 bf16 per lane, shuffle reduce
// ---------------------------------------------------------------------------
__global__ __launch_bounds__(256)
void k_pet(const unsigned short* __restrict__ xb, const int* __restrict__ ei,
           const float* __restrict__ ew, const float* __restrict__ etW,
           const float* __restrict__ etb, float* __restrict__ out, int E)
{
    const int lane = threadIdx.x & 63;
    const long wg = ((long)blockIdx.x * blockDim.x + threadIdx.x) >> 6;
    const long e = wg * 4 + (lane >> 4);
    const int l16 = lane & 15;
    if (e >= E) return;
    const int s = ei[e], d = ei[E + e];
    uint4 av = ((const uint4*)(xb + (size_t)s * 128))[l16];
    uint4 bv = ((const uint4*)(xb + (size_t)d * 128))[l16];
    bf16x8 a = __builtin_bit_cast(bf16x8, av);
    bf16x8 b = __builtin_bit_cast(bf16x8, bv);
    float4 w0 = ((const float4*)etW)[l16 * 2];
    float4 w1 = ((const float4*)etW)[l16 * 2 + 1];
    float acc = fabsf((float)a[0] - (float)b[0]) * w0.x
              + fabsf((float)a[1] - (float)b[1]) * w0.y
              + fabsf((float)a[2] - (float)b[2]) * w0.z
              + fabsf((float)a[3] - (float)b[3]) * w0.w
              + fabsf((float)a[4] - (float)b[4]) * w1.x
              + fabsf((float)a[5] - (float)b[5]) * w1.y
              + fabsf((float)a[6] - (float)b[6]) * w1.z
              + fabsf((float)a[7] - (float)b[7]) * w1.w;
    acc += __shfl_xor(acc, 8);
    acc += __shfl_xor(acc, 4);
    acc += __shfl_xor(acc, 2);
    acc += __shfl_xor(acc, 1);
    if (l16 == 0)
        out[e] = acc + ew[2 * e] * etW[128] + ew[2 * e + 1] * etW[129] + etb[0];
}

// ---------------------------------------------------------------------------
extern "C" void kernel_launch(void* const* d_in, const int* in_sizes, int n_in,
                              void* d_out, int out_size, void* d_ws, size_t ws_size,
                              hipStream_t stream) {
    const float* x   = (const float*)d_in[0];
    const int*   ei  = (const int*)d_in[1];
    const float* ew  = (const float*)d_in[2];
    const float* Wc1 = (const float*)d_in[3];
    const float* bc1 = (const float*)d_in[4];
    const float* W1  = (const float*)d_in[5];
    const float* b1  = (const float*)d_in[6];
    const float* Wc2 = (const float*)d_in[7];
    const float* bc2 = (const float*)d_in[8];
    const float* W2  = (const float*)d_in[9];
    const float* b2  = (const float*)d_in[10];
    const float* Wc3 = (const float*)d_in[11];
    const float* bc3 = (const float*)d_in[12];
    const float* W3  = (const float*)d_in[13];
    const float* b3  = (const float*)d_in[14];
    const float* Wc4 = (const float*)d_in[15];
    const float* bc4 = (const float*)d_in[16];
    const float* W4  = (const float*)d_in[17];
    const float* b4  = (const float*)d_in[18];
    const float* etW = (const float*)d_in[19];
    const float* etb = (const float*)d_in[20];

    float* out   = (float*)d_out;
    float* recon = out;                              // N x 128
    float* mu    = out + (size_t)NN * 128;           // N x 64
    float* lv    = mu + (size_t)NN * 64;             // N x 64
    float* pet   = lv + (size_t)NN * 64;             // E x 1

    char* wsp = (char*)d_ws;
    unsigned short* xb  = (unsigned short*)(wsp);              // 12.8 MB
    unsigned short* Yb  = (unsigned short*)(wsp + 12800000);   // 12.8 MB (scratch Y)
    unsigned short* ab  = (unsigned short*)(wsp + 25600000);   // 12.8 MB (scratch mean)
    unsigned short* h1b = (unsigned short*)(wsp + 38400000);   // 12.8 MB
    unsigned short* zb  = (unsigned short*)(wsp + 51200000);   // 6.4 MB
    unsigned short* db  = (unsigned short*)(wsp + 57600000);   // 12.8 MB
    int* deg            = (int*)(wsp + 70400000);              // 0.2 MB
    int* cursor         = (int*)(wsp + 70600000);              // 0.2 MB
    int* srcS           = (int*)(wsp + 70800000);              // 3.2 MB
    float2* ewS         = (float2*)(wsp + 74000000);           // 6.4 MB
    int* part           = (int*)(wsp + 80400000);              // 1 KB

    const int E = NE, NV = NN;

    // ---- precompute: degree, hierarchical scan, dst-sorted (srcS, ewS), bf16 x
    hipMemsetAsync(deg, 0, NV * sizeof(int), stream);
    k_deg<<<(E + 255) / 256, 256, 0, stream>>>(ei, deg, E);
    k_scan1<<<256, 256, 0, stream>>>(deg, part, NV);
    k_scan2<<<1, 256, 0, stream>>>(part);
    k_scan3<<<256, 256, 0, stream>>>(deg, part, cursor, NV);
    k_scatter<<<(E + 255) / 256, 256, 0, stream>>>(ei, ew, cursor, srcS, ewS, E);
    k_cvt<<<(800000 + 255) / 256, 256, 0, stream>>>(x, xb, 800000);

    // ---- conv1: Y1 = xb@Wc1 ; mean ; h1 = relu(mean@W1+b1)
    k_dense<128, 128, 0><<<391, 256, 0, stream>>>(xb, Wc1, nullptr,
                                                  nullptr, nullptr, Yb, NV);
    k_agg<128><<<12500, 256, 0, stream>>>(Yb, srcS, ewS, Wc1 + 128 * 128, bc1,
                                          cursor, deg, ab, NV);
    k_dense<128, 128, 1><<<391, 256, 0, stream>>>(ab, W1, b1,
                                                  nullptr, nullptr, h1b, NV);

    // ---- conv2: Y2 = h1@Wc2 ; mean ; (mu, logvar, z) = relu(mean@W2+b2)
    k_dense<128, 128, 0><<<391, 256, 0, stream>>>(h1b, Wc2, nullptr,
                                                  nullptr, nullptr, Yb, NV);
    k_agg<128><<<12500, 256, 0, stream>>>(Yb, srcS, ewS, Wc2 + 128 * 128, bc2,
                                          cursor, deg, ab, NV);
    k_dense<128, 128, 2><<<391, 256, 0, stream>>>(ab, W2, b2,
                                                  mu, lv, zb, NV);

    // ---- pet (bf16 xb)
    k_pet<<<50000, 256, 0, stream>>>(xb, ei, ew, etW, etb, pet, E);

    // ---- conv3: Y3 = zb@Wc3 ; mean ; d = relu(mean@W3+b3)
    k_dense<64, 64, 0><<<391, 256, 0, stream>>>(zb, Wc3, nullptr,
                                                nullptr, nullptr, Yb, NV);
    k_agg<64><<<12500, 256, 0, stream>>>(Yb, srcS, ewS, Wc3 + 64 * 64, bc3,
                                         cursor, deg, ab, NV);
    k_dense<64, 128, 1><<<391, 256, 0, stream>>>(ab, W3, b3,
                                                 nullptr, nullptr, db, NV);

    // ---- conv4: Y4 = db@Wc4 ; mean ; recon = tanh(mean@W4+b4)
    k_dense<128, 128, 0><<<391, 256, 0, stream>>>(db, Wc4, nullptr,
                                                  nullptr, nullptr, Yb, NV);
    k_agg<128><<<12500, 256, 0, stream>>>(Yb, srcS, ewS, Wc4 + 128 * 128, bc4,
                                          cursor, deg, ab, NV);
    k_dense<128, 128, 3><<<391, 256, 0, stream>>>(ab, W4, b4,
                                                  recon, nullptr, nullptr, NV);
}